// Round 25
// baseline (135.960 us; speedup 1.0000x reference)
//
#include <hip/hip_runtime.h>
#include <hip/hip_bf16.h>

typedef __attribute__((ext_vector_type(8))) short bh8;   // 8 bf16 in 4 VGPRs
typedef __attribute__((ext_vector_type(4))) float f4;    // MFMA accumulator

typedef unsigned short u16;
typedef unsigned int u32;

__device__ inline u16 f2b(float f) {
  __hip_bfloat16 h = __float2bfloat16(f);
  union { __hip_bfloat16 h; u16 u; } v; v.h = h; return v.u;
}
__device__ inline float b2f(u16 b) {
  union { u32 u; float f; } v; v.u = ((u32)b) << 16;
  return v.f;
}

// async global->LDS, 16B per lane; LDS dest is wave-uniform base + lane*16
__device__ __forceinline__ void gload16(const u16* g, u16* l) {
  __builtin_amdgcn_global_load_lds(
      (__attribute__((address_space(1))) void*)(g),
      (__attribute__((address_space(3))) void*)(l),
      16, 0, 0);
}

// ---------------- fused prep 1: cast x to bf16 (fat blocks) + both weight transposes ----------------
__global__ __launch_bounds__(256) void k_prep1(const float* __restrict__ x,
                                               const float* __restrict__ Wqkv,
                                               const float* __restrict__ Wo,
                                               u16* __restrict__ xb,
                                               u16* __restrict__ wqkvT,
                                               u16* __restrict__ woT) {
  int idx = blockIdx.x;
  if (idx < 2048) {
    int i = (idx * 256 + threadIdx.x) * 8;
    float4 v0 = *(const float4*)&x[i];
    float4 v1 = *(const float4*)&x[i + 4];
    ushort4 o0, o1;
    o0.x = f2b(v0.x); o0.y = f2b(v0.y); o0.z = f2b(v0.z); o0.w = f2b(v0.w);
    o1.x = f2b(v1.x); o1.y = f2b(v1.y); o1.z = f2b(v1.z); o1.w = f2b(v1.w);
    *(ushort4*)&xb[i]     = o0;
    *(ushort4*)&xb[i + 4] = o1;
    return;
  }
  __shared__ u16 t[32][33];
  const float* W; u16* WT; int K, N, bxi, byi;
  if (idx < 5120) {
    int id2 = idx - 2048;               // 96 x 32
    W = Wqkv; WT = wqkvT; K = 1024; N = 3072;
    bxi = id2 % 96; byi = id2 / 96;
  } else {
    int id2 = idx - 5120;               // 32 x 32
    W = Wo; WT = woT; K = 1024; N = 1024;
    bxi = id2 & 31; byi = id2 >> 5;
  }
  int bx = bxi * 32, by = byi * 32;
  int xx = threadIdx.x & 31, yy = threadIdx.x >> 5;
  for (int j = 0; j < 4; ++j) {
    int r = yy + j * 8;
    t[r][xx] = f2b(W[(size_t)(by + r) * N + bx + xx]);
  }
  __syncthreads();
  for (int j = 0; j < 4; ++j) {
    int r = yy + j * 8;
    WT[(size_t)(bx + r) * K + by + xx] = t[xx][r];
  }
}

// ---------------- GEMM 128x128, XOR-swizzled LDS + XCD-grouped blocks — GEMM1 ----------------
template <bool F32OUT>
__global__ __launch_bounds__(256) void k_gemm(const u16* __restrict__ A,
                                              const u16* __restrict__ Bt,
                                              void* __restrict__ Cout,
                                              int M, int N, int K) {
  __shared__ u16 As[2][128 * 64];
  __shared__ u16 Bs[2][128 * 64];
  const int tid = threadIdx.x;
  const int lane = tid & 63, wid = tid >> 6;
  const int l15 = lane & 15, lg = lane >> 4;

  // bijective XCD swizzle (grid %8 == 0): each XCD gets a contiguous chunk of
  // block-ids -> neighboring tiles (shared A/B panels) land in the same L2.
  int nwg = gridDim.x * gridDim.y;
  int bid = blockIdx.y * gridDim.x + blockIdx.x;
  int cpx = nwg >> 3;
  int swz = (bid & 7) * cpx + (bid >> 3);
  int bx = swz % gridDim.x, by = swz / gridDim.x;
  const int bm = bx * 128, bn = by * 128;
  const int wr = (wid >> 1) * 64, wc = (wid & 1) * 64;

  f4 acc[4][4] = {};

  const int srow = wid * 32 + (lane >> 3);
  const int scol = ((lane & 7) ^ ((lane >> 3) & 7)) * 8;
  const u16* gA = A  + (size_t)(bm + srow) * K + scol;
  const u16* gB = Bt + (size_t)(bn + srow) * K + scol;

  const int nk = K >> 6;

  {
    const u16* ga = gA; const u16* gb = gB;
    u16* la = &As[0][(wid * 32) * 64];
    u16* lb = &Bs[0][(wid * 32) * 64];
    #pragma unroll
    for (int c = 0; c < 4; ++c) {
      gload16(ga, la);
      gload16(gb, lb);
      ga += (size_t)8 * K; gb += (size_t)8 * K;
      la += 8 * 64;        lb += 8 * 64;
    }
  }
  __syncthreads();

  for (int t = 0; t < nk; ++t) {
    if (t + 1 < nk) {
      int kb = (t + 1) << 6;
      const u16* ga = gA + kb; const u16* gb = gB + kb;
      u16* la = &As[(t + 1) & 1][(wid * 32) * 64];
      u16* lb = &Bs[(t + 1) & 1][(wid * 32) * 64];
      #pragma unroll
      for (int c = 0; c < 4; ++c) {
        gload16(ga, la);
        gload16(gb, lb);
        ga += (size_t)8 * K; gb += (size_t)8 * K;
        la += 8 * 64;        lb += 8 * 64;
      }
    }
    const u16* as = &As[t & 1][0];
    const u16* bs = &Bs[t & 1][0];
    #pragma unroll
    for (int kk = 0; kk < 2; ++kk) {
      bh8 a[4], b[4];
      #pragma unroll
      for (int m = 0; m < 4; ++m)
        a[m] = *(const bh8*)&as[(wr + m * 16 + l15) * 64 + (((kk * 4 + lg) ^ (l15 & 7)) * 8)];
      #pragma unroll
      for (int n = 0; n < 4; ++n)
        b[n] = *(const bh8*)&bs[(wc + n * 16 + l15) * 64 + (((kk * 4 + lg) ^ (l15 & 7)) * 8)];
      #pragma unroll
      for (int m = 0; m < 4; ++m)
        #pragma unroll
        for (int n = 0; n < 4; ++n)
          acc[m][n] = __builtin_amdgcn_mfma_f32_16x16x32_bf16(a[m], b[n], acc[m][n], 0, 0, 0);
    }
    __syncthreads();
  }

  for (int m = 0; m < 4; ++m)
    for (int n = 0; n < 4; ++n)
      for (int r = 0; r < 4; ++r) {
        int row = bm + wr + m * 16 + lg * 4 + r;
        int col = bn + wc + n * 16 + l15;
        float v = acc[m][n][r];
        if constexpr (F32OUT) ((float*)Cout)[(size_t)row * N + col] = v;
        else                  ((u16*)Cout)[(size_t)row * N + col]  = f2b(v);
      }
}

// ---------------- GEMM2: 64x128 tile + XCD-grouped blocks; 512 blocks, 8 waves/CU ----------------
__global__ __launch_bounds__(256) void k_gemm64(const u16* __restrict__ A,
                                                const u16* __restrict__ Bt,
                                                float* __restrict__ Cout,
                                                int M, int N, int K) {
  __shared__ u16 As[2][64 * 64];    // 16 KB
  __shared__ u16 Bs[2][128 * 64];   // 32 KB
  const int tid = threadIdx.x;
  const int lane = tid & 63, wid = tid >> 6;
  const int l15 = lane & 15, lg = lane >> 4;

  int nwg = gridDim.x * gridDim.y;
  int bid = blockIdx.y * gridDim.x + blockIdx.x;
  int cpx = nwg >> 3;
  int swz = (bid & 7) * cpx + (bid >> 3);
  int bx = swz % gridDim.x, by = swz / gridDim.x;
  const int bm = bx * 64, bn = by * 128;
  const int wr = (wid >> 1) * 32, wc = (wid & 1) * 64;

  f4 acc[2][4] = {};

  const int arow = wid * 16 + (lane >> 3);
  const int brow = wid * 32 + (lane >> 3);
  const int scol = ((lane & 7) ^ ((lane >> 3) & 7)) * 8;   // all staged rows ≡ (lane>>3) mod 8
  const u16* gA = A  + (size_t)(bm + arow) * K + scol;
  const u16* gB = Bt + (size_t)(bn + brow) * K + scol;

  const int nk = K >> 6;

#define STAGE64(T)                                                 \
  {                                                                \
    int kb_ = (T) << 6; int bf_ = (T) & 1;                         \
    u16* la = &As[bf_][(wid * 16) * 64];                           \
    gload16(gA + kb_, la);                                         \
    gload16(gA + kb_ + (size_t)8 * K, la + 8 * 64);                \
    u16* lb = &Bs[bf_][(wid * 32) * 64];                           \
    const u16* gb = gB + kb_;                                      \
    _Pragma("unroll")                                              \
    for (int c = 0; c < 4; ++c) {                                  \
      gload16(gb, lb);                                             \
      gb += (size_t)8 * K; lb += 8 * 64;                           \
    }                                                              \
  }

  STAGE64(0);
  __syncthreads();

  for (int t = 0; t < nk; ++t) {
    if (t + 1 < nk) STAGE64(t + 1);
    const u16* as = &As[t & 1][0];
    const u16* bs = &Bs[t & 1][0];
    #pragma unroll
    for (int kk = 0; kk < 2; ++kk) {
      bh8 a[2], b[4];
      #pragma unroll
      for (int m = 0; m < 2; ++m)
        a[m] = *(const bh8*)&as[(wr + m * 16 + l15) * 64 + (((kk * 4 + lg) ^ (l15 & 7)) * 8)];
      #pragma unroll
      for (int n = 0; n < 4; ++n)
        b[n] = *(const bh8*)&bs[(wc + n * 16 + l15) * 64 + (((kk * 4 + lg) ^ (l15 & 7)) * 8)];
      #pragma unroll
      for (int m = 0; m < 2; ++m)
        #pragma unroll
        for (int n = 0; n < 4; ++n)
          acc[m][n] = __builtin_amdgcn_mfma_f32_16x16x32_bf16(a[m], b[n], acc[m][n], 0, 0, 0);
    }
    __syncthreads();
  }
#undef STAGE64

  for (int m = 0; m < 2; ++m)
    for (int n = 0; n < 4; ++n)
      for (int r = 0; r < 4; ++r) {
        int row = bm + wr + m * 16 + lg * 4 + r;
        int col = bn + wc + n * 16 + l15;
        Cout[(size_t)row * N + col] = acc[m][n][r];
      }
}

// ---------------- fused prep 2: vectorized RMSNorm+RoPE (Q,K) + vectorized V transpose ----------------
__global__ __launch_bounds__(256) void k_prep2(const u16* __restrict__ qkv,
                                               const float* __restrict__ qw,
                                               const float* __restrict__ kw,
                                               const float* __restrict__ cosp,
                                               const float* __restrict__ sinp,
                                               u16* __restrict__ Q,
                                               u16* __restrict__ K,
                                               u16* __restrict__ Vt) {
  const float CSC = 0.125f * 1.44269504088896f;
  int idx = blockIdx.x;
  if (idx < 2048) {
    int wid = threadIdx.x >> 6, lane = threadIdx.x & 63;
    int gw = idx * 4 + wid;
    int isK = gw & 1;
    int bl = gw >> 1;
    int l = bl & 2047, b = bl >> 11;
    int h = lane >> 2, qd = lane & 3;
    const u16* src = qkv + (size_t)bl * 3072 + isK * 1024 + h * 64 + qd * 8;
    bh8 t1 = *(const bh8*)src;
    bh8 t2 = *(const bh8*)(src + 32);
    float a1[8], a2[8];
    float ss = 0.0f;
    #pragma unroll
    for (int j = 0; j < 8; ++j) {
      a1[j] = b2f((u16)t1[j]); a2[j] = b2f((u16)t2[j]);
      ss += a1[j] * a1[j] + a2[j] * a2[j];
    }
    ss += __shfl_xor(ss, 1, 64);
    ss += __shfl_xor(ss, 2, 64);
    float rr = rsqrtf(ss * (1.0f / 64.0f) + 1e-6f);
    const float* wt = isK ? kw : qw;
    float w1[8], w2[8], cc[8], sn[8];
    *(float4*)&w1[0] = *(const float4*)&wt[qd * 8];
    *(float4*)&w1[4] = *(const float4*)&wt[qd * 8 + 4];
    *(float4*)&w2[0] = *(const float4*)&wt[32 + qd * 8];
    *(float4*)&w2[4] = *(const float4*)&wt[32 + qd * 8 + 4];
    *(float4*)&cc[0] = *(const float4*)&cosp[l * 32 + qd * 8];
    *(float4*)&cc[4] = *(const float4*)&cosp[l * 32 + qd * 8 + 4];
    *(float4*)&sn[0] = *(const float4*)&sinp[l * 32 + qd * 8];
    *(float4*)&sn[4] = *(const float4*)&sinp[l * 32 + qd * 8 + 4];
    float scl = isK ? 1.0f : CSC;
    bh8 o1, o2;
    #pragma unroll
    for (int j = 0; j < 8; ++j) {
      float x1 = a1[j] * rr * w1[j];
      float x2 = a2[j] * rr * w2[j];
      o1[j] = (short)f2b((x1 * cc[j] - x2 * sn[j]) * scl);
      o2[j] = (short)f2b((x1 * sn[j] + x2 * cc[j]) * scl);
    }
    u16* dst = (isK ? K : Q) + ((size_t)(b * 16 + h) * 2048 + l) * 64 + qd * 8;
    *(bh8*)dst = o1;
    *(bh8*)(dst + 32) = o2;
  } else {
    // vectorized V transpose: [64 l][64 d] tile per block, bh8 on both global sides
    __shared__ u16 tt[64][66];
    int v = idx - 2048;                 // 0..1023: bh (32) x l-tile (32)
    int bh = v >> 5, lt = v & 31;
    int b = bh >> 4, h = bh & 15;
    int lb = lt * 64;
    const u16* src = qkv + (size_t)b * 2048 * 3072 + 2048 + h * 64;
    int r0 = threadIdx.x >> 3, c0 = (threadIdx.x & 7) * 8;
    *(bh8*)&tt[r0][c0]      = *(const bh8*)&src[(size_t)(lb + r0) * 3072 + c0];
    *(bh8*)&tt[r0 + 32][c0] = *(const bh8*)&src[(size_t)(lb + r0 + 32) * 3072 + c0];
    __syncthreads();
    u16* dst = Vt + (size_t)bh * 64 * 2048;
    int d0 = threadIdx.x >> 3, l0 = (threadIdx.x & 7) * 8;
    bh8 o0, o1;
    #pragma unroll
    for (int j = 0; j < 8; ++j) {
      o0[j] = (short)tt[l0 + j][d0];
      o1[j] = (short)tt[l0 + j][d0 + 32];
    }
    *(bh8*)&dst[(size_t)d0 * 2048 + lb + l0]        = o0;
    *(bh8*)&dst[(size_t)(d0 + 32) * 2048 + lb + l0] = o1;
  }
}

// ---------------- flash attention, causal; R17 proven best (XCD-grouped bh, defer-max) ----------------
__global__ __launch_bounds__(256, 3) void k_attn(const u16* __restrict__ Q,
                                                 const u16* __restrict__ K,
                                                 const u16* __restrict__ Vt,
                                                 u16* __restrict__ O,
                                                 u16* __restrict__ Opart,
                                                 float2* __restrict__ Ml) {
  __shared__ u16 Ks[2][64 * 64];   // [k-local][d], XOR-swizzled chunks
  __shared__ u16 Vs[2][64 * 64];   // [d][k-local], XOR-swizzled chunks
  __shared__ u16 Pl[4][32][64];    // per-wave P, XOR-swizzled 16B chunks

  const int wid = threadIdx.x >> 6, lane = threadIdx.x & 63;
  const int l15 = lane & 15, lg = lane >> 4;

  // XCD-grouped block remap (1472 = 8 XCD * 4 bh * 46 chunks)
  const int linear = (int)blockIdx.y * 46 + (int)blockIdx.x;
  const int xcd = linear & 7;
  const int rest = linear >> 3;
  const int bh = xcd * 4 + (rest & 3);
  const int chunkIdx = rest >> 2;          // 0..45; chunk 0 of all bh dispatch first
  const int b = bh >> 4, h = bh & 15;

  const int ctab[17] = {0,1,2,3,5,7,9,11,14,17,20,24,28,32,36,41,46};
  const int id = 45 - chunkIdx;            // longest chunks first
  int qt = 0;
  #pragma unroll
  for (int qq = 0; qq < 16; ++qq)
    if (id >= ctab[qq + 1]) qt = qq + 1;
  const int part = id - ctab[qt];
  const int ways = ctab[qt + 1] - ctab[qt];
  const int T = 2 * qt + 2;
  const int t0 = part * T / ways;
  const int t1 = (part + 1) * T / ways;
  const int slot = (ways == 1) ? -1 : bh * 43 + (id - 3);

  const int qb = qt * 128 + wid * 32;

  const u16* Qp = Q  + (size_t)bh * 2048 * 64;
  const u16* Kp = K  + (size_t)bh * 2048 * 64;
  const u16* Vp = Vt + (size_t)bh * 64 * 2048;

  const int sr0 = wid * 8 + (lane >> 3);
  const int sc  = lane & 7;

  bh8 aq[2][2];
  #pragma unroll
  for (int qi = 0; qi < 2; ++qi)
    #pragma unroll
    for (int hh = 0; hh < 2; ++hh)
      aq[qi][hh] = *(const bh8*)&Qp[(size_t)(qb + qi * 16 + l15) * 64 + hh * 32 + lg * 8];

  bh8 ones;
  #pragma unroll
  for (int j = 0; j < 8; ++j) ones[j] = (short)0x3F80;

  f4 acc[2][4] = {};
  float mrow[2] = {-1e30f, -1e30f};   // log2 domain
  float lrow[2] = {0.0f, 0.0f};

  const int tmax = (qb + 31) >> 6;

  // prologue: stage tile t0
  {
    int kb0 = t0 * 64;
    int r0 = sr0, r1 = 32 + sr0;
    gload16(Kp + (size_t)(kb0 + r0) * 64 + (size_t)((sc ^ (r0 & 7)) * 8), &Ks[t0 & 1][(wid * 8) * 64]);
    gload16(Kp + (size_t)(kb0 + r1) * 64 + (size_t)((sc ^ (r1 & 7)) * 8), &Ks[t0 & 1][(32 + wid * 8) * 64]);
    gload16(Vp + (size_t)r0 * 2048 + kb0 + (size_t)((sc ^ (r0 & 7)) * 8), &Vs[t0 & 1][(wid * 8) * 64]);
    gload16(Vp + (size_t)r1 * 2048 + kb0 + (size_t)((sc ^ (r1 & 7)) * 8), &Vs[t0 & 1][(32 + wid * 8) * 64]);
  }
  __syncthreads();

  for (int t = t0; t < t1; ++t) {
    if (t + 1 < t1) {
      int kb = (t + 1) * 64;
      int nb = (t + 1) & 1;
      int r0 = sr0, r1 = 32 + sr0;
      gload16(Kp + (size_t)(kb + r0) * 64 + (size_t)((sc ^ (r0 & 7)) * 8), &Ks[nb][(wid * 8) * 64]);
      gload16(Kp + (size_t)(kb + r1) * 64 + (size_t)((sc ^ (r1 & 7)) * 8), &Ks[nb][(32 + wid * 8) * 64]);
      gload16(Vp + (size_t)r0 * 2048 + kb + (size_t)((sc ^ (r0 & 7)) * 8), &Vs[nb][(wid * 8) * 64]);
      gload16(Vp + (size_t)r1 * 2048 + kb + (size_t)((sc ^ (r1 & 7)) * 8), &Vs[nb][(32 + wid * 8) * 64]);
    }
    if (t <= tmax) {
      const int kb = t * 64;
      const bool masked = (t == tmax);
      const u16* ks = &Ks[t & 1][0];
      const u16* vs = &Vs[t & 1][0];

      // ---- QK^T (swapped): D col=q; Q pre-scaled (log2 domain) ----
      f4 sc4[4][2] = {};
      __builtin_amdgcn_s_setprio(1);
      #pragma unroll
      for (int kq = 0; kq < 4; ++kq) {
        int row = kq * 16 + l15;
        int cs = row & 7;
        bh8 ka0 = *(const bh8*)&ks[row * 64 + ((0 + lg) ^ cs) * 8];
        bh8 ka1 = *(const bh8*)&ks[row * 64 + ((4 + lg) ^ cs) * 8];
        #pragma unroll
        for (int qi = 0; qi < 2; ++qi) {
          sc4[kq][qi] = __builtin_amdgcn_mfma_f32_16x16x32_bf16(ka0, aq[qi][0], sc4[kq][qi], 0, 0, 0);
          sc4[kq][qi] = __builtin_amdgcn_mfma_f32_16x16x32_bf16(ka1, aq[qi][1], sc4[kq][qi], 0, 0, 0);
        }
      }
      __builtin_amdgcn_s_setprio(0);

      // ---- online softmax (log2 domain), defer-max THR=8, mask only diag ----
      #pragma unroll
      for (int qi = 0; qi < 2; ++qi) {
        if (masked) {
          int q = qb + qi * 16 + l15;
          #pragma unroll
          for (int kq = 0; kq < 4; ++kq)
            #pragma unroll
            for (int r = 0; r < 4; ++r)
              if (kb + kq * 16 + lg * 4 + r > q) sc4[kq][qi][r] = -1e30f;
        }
        float mx = -1e30f;
        #pragma unroll
        for (int kq = 0; kq < 4; ++kq)
          #pragma unroll
          for (int r = 0; r < 4; ++r)
            mx = fmaxf(mx, sc4[kq][qi][r]);
        mx = fmaxf(mx, __shfl_xor(mx, 16, 64));
        mx = fmaxf(mx, __shfl_xor(mx, 32, 64));
        if (__any(mx > mrow[qi] + 8.0f)) {
          float mnew = fmaxf(mrow[qi], mx);
          float fac = exp2f(mrow[qi] - mnew);
          mrow[qi] = mnew;
          lrow[qi] *= fac;
          #pragma unroll
          for (int n = 0; n < 4; ++n)
            #pragma unroll
            for (int r = 0; r < 4; ++r) acc[qi][n][r] *= fac;
        }
        #pragma unroll
        for (int kq = 0; kq < 4; ++kq)
          #pragma unroll
          for (int r = 0; r < 4; ++r)
            sc4[kq][qi][r] = exp2f(sc4[kq][qi][r] - mrow[qi]);
      }

      // ---- P -> per-wave LDS (XOR-swizzled 16B chunks; DS pipe) ----
      char* plb = (char*)&Pl[wid][0][0];
      #pragma unroll
      for (int qi = 0; qi < 2; ++qi) {
        int row = qi * 16 + l15;
        #pragma unroll
        for (int kq = 0; kq < 4; ++kq) {
          ushort4 w4;
          w4.x = f2b(sc4[kq][qi][0]); w4.y = f2b(sc4[kq][qi][1]);
          w4.z = f2b(sc4[kq][qi][2]); w4.w = f2b(sc4[kq][qi][3]);
          int ch = (kq * 2 + (lg >> 1)) ^ (row & 7);
          *(ushort4*)(plb + row * 128 + ch * 16 + (lg & 1) * 8) = w4;
        }
      }
      asm volatile("s_waitcnt lgkmcnt(0)" ::: "memory");
      __builtin_amdgcn_sched_barrier(0);

      // ---- PV (double-swapped) + row-sum via ones-MFMA ----
      f4 sum0 = {}, sum1 = {};
      __builtin_amdgcn_s_setprio(1);
      #pragma unroll
      for (int g = 0; g < 2; ++g) {
        bh8 pb0 = *(const bh8*)(plb + l15 * 128 + (((g * 4 + lg) ^ (l15 & 7)) * 16));
        bh8 pb1 = *(const bh8*)(plb + (16 + l15) * 128 + (((g * 4 + lg) ^ (l15 & 7)) * 16));
        #pragma unroll
        for (int n = 0; n < 4; ++n) {
          int row = n * 16 + l15;
          bh8 va = *(const bh8*)&vs[row * 64 + (((g * 4 + lg) ^ (row & 7)) * 8)];
          acc[0][n] = __builtin_amdgcn_mfma_f32_16x16x32_bf16(va, pb0, acc[0][n], 0, 0, 0);
          acc[1][n] = __builtin_amdgcn_mfma_f32_16x16x32_bf16(va, pb1, acc[1][n], 0, 0, 0);
        }
        sum0 = __builtin_amdgcn_mfma_f32_16x16x32_bf16(ones, pb0, sum0, 0, 0, 0);
        sum1 = __builtin_amdgcn_mfma_f32_16x16x32_bf16(ones, pb1, sum1, 0, 0, 0);
      }
      __builtin_amdgcn_s_setprio(0);
      lrow[0] += sum0[0];
      lrow[1] += sum1[0];
    }
    __syncthreads();
  }

  if (slot < 0) {
    #pragma unroll
    for (int qi = 0; qi < 2; ++qi) {
      float inv = 1.0f / lrow[qi];
      int q = qb + qi * 16 + l15;
      #pragma unroll
      for (int n = 0; n < 4; ++n) {
        ushort4 w4;
        w4.x = f2b(acc[qi][n][0] * inv);
        w4.y = f2b(acc[qi][n][1] * inv);
        w4.z = f2b(acc[qi][n][2] * inv);
        w4.w = f2b(acc[qi][n][3] * inv);
        *(ushort4*)&O[((size_t)b * 2048 + q) * 1024 + h * 64 + n * 16 + lg * 4] = w4;
      }
    }
  } else {
    u16* op = Opart + (size_t)slot * 8192;
    #pragma unroll
    for (int qi = 0; qi < 2; ++qi) {
      int rloc = wid * 32 + qi * 16 + l15;
      #pragma unroll
      for (int n = 0; n < 4; ++n) {
        ushort4 w4;
        w4.x = f2b(acc[qi][n][0]); w4.y = f2b(acc[qi][n][1]);
        w4.z = f2b(acc[qi][n][2]); w4.w = f2b(acc[qi][n][3]);
        *(ushort4*)&op[(size_t)rloc * 64 + n * 16 + lg * 4] = w4;
      }
      if (lg == 0) Ml[slot * 128 + rloc] = make_float2(mrow[qi], lrow[qi]);
    }
  }
}

// ---------------- combine split-K partials (2..5-way, 128-row slots) ----------------
__global__ __launch_bounds__(256) void k_comb(const u16* __restrict__ Opart,
                                              const float2* __restrict__ Ml,
                                              u16* __restrict__ O) {
  const int ctab[17] = {0,1,2,3,5,7,9,11,14,17,20,24,28,32,36,41,46};
  int qt = 3 + (int)blockIdx.x;     // 3..15
  int bh = blockIdx.y;
  int b = bh >> 4, h = bh & 15;
  int ways = ctab[qt + 1] - ctab[qt];
  int base = bh * 43 + ctab[qt] - 3;
  int row = threadIdx.x >> 1;
  int db  = (threadIdx.x & 1) * 32;

  float2 ml[5]; float wgt[5];
  float M = -1e30f;
  #pragma unroll
  for (int w = 0; w < 5; ++w)
    if (w < ways) { ml[w] = Ml[(base + w) * 128 + row]; M = fmaxf(M, ml[w].x); }
  float l = 0.0f;
  #pragma unroll
  for (int w = 0; w < 5; ++w)
    if (w < ways) { wgt[w] = exp2f(ml[w].x - M); l += wgt[w] * ml[w].y; }
  float inv = 1.0f / l;

  u16* dst = O + ((size_t)b * 2048 + qt * 128 + row) * 1024 + h * 64 + db;
  #pragma unroll
  for (int j = 0; j < 32; j += 8) {
    float a[8] = {};
    #pragma unroll
    for (int w = 0; w < 5; ++w)
      if (w < ways) {
        bh8 v = *(const bh8*)&Opart[(size_t)(base + w) * 8192 + (size_t)row * 64 + db + j];
        #pragma unroll
        for (int e = 0; e < 8; ++e) a[e] += wgt[w] * b2f((u16)v[e]);
      }
    bh8 o;
    #pragma unroll
    for (int e = 0; e < 8; ++e) o[e] = (short)f2b(a[e] * inv);
    *(bh8*)&dst[j] = o;
  }
}

extern "C" void kernel_launch(void* const* d_in, const int* in_sizes, int n_in,
                              void* d_out, int out_size, void* d_ws, size_t ws_size,
                              hipStream_t stream) {
  (void)in_sizes; (void)n_in; (void)out_size; (void)ws_size;
  const float* x    = (const float*)d_in[0];
  const float* Wqkv = (const float*)d_in[1];
  const float* Wo   = (const float*)d_in[2];
  const float* qw   = (const float*)d_in[3];
  const float* kw   = (const float*)d_in[4];
  const float* cosp = (const float*)d_in[5];
  const float* sinp = (const float*)d_in[6];
  float* out = (float*)d_out;

  char* ws = (char*)d_ws;
  u16* xb    = (u16*)(ws);                 //  8,388,608 B  x bf16 [4096][1024]
  u16* wqkvT = (u16*)(ws + 8388608);       //  6,291,456 B  Wqkv^T bf16
  u16* woT   = (u16*)(ws + 14680064);      //  2,097,152 B  Wo^T bf16
  u16* qkv   = (u16*)(ws + 16777216);      // 25,165,824 B  qkv bf16 [4096][3072]
  u16* Qb    = (u16*)(ws + 41943040);      //  8,388,608 B  [B,H,L,D]
  u16* Kb    = (u16*)(ws + 50331648);      //  8,388,608 B
  u16* Vtb   = (u16*)(ws + 58720256);      //  8,388,608 B  [B,H,D,L]
  u16* AO    = (u16*)(ws + 67108864);      //  8,388,608 B  attn_out bf16
  // split-K partials overlay the dead qkv region:
  // 1376 slots * 8192 u16 * 2B = 22,544,384 B; Ml after it (1,409,024 B); total < 25,165,824 B
  u16*    Opart = (u16*)(ws + 16777216);
  float2* Mlb   = (float2*)(ws + 16777216 + 22544384);

  k_prep1<<<6144, 256, 0, stream>>>(x, Wqkv, Wo, xb, wqkvT, woT);
  k_gemm<false><<<dim3(32, 24), 256, 0, stream>>>(xb, wqkvT, qkv, 4096, 3072, 1024);
  k_prep2<<<3072, 256, 0, stream>>>(qkv, qw, kw, cosp, sinp, Qb, Kb, Vtb);
  k_attn<<<dim3(46, 32), 256, 0, stream>>>(Qb, Kb, Vtb, AO, Opart, Mlb);
  k_comb<<<dim3(13, 32), 256, 0, stream>>>(Opart, Mlb, AO);
  k_gemm64<<<dim3(64, 8), 256, 0, stream>>>(AO, woT, out, 4096, 1024, 1024);
}

// Round 26
// 133.533 us; speedup vs baseline: 1.0182x; 1.0182x over previous
//
#include <hip/hip_runtime.h>
#include <hip/hip_bf16.h>

typedef __attribute__((ext_vector_type(8))) short bh8;   // 8 bf16 in 4 VGPRs
typedef __attribute__((ext_vector_type(4))) float f4;    // MFMA accumulator

typedef unsigned short u16;
typedef unsigned int u32;

__device__ inline u16 f2b(float f) {
  __hip_bfloat16 h = __float2bfloat16(f);
  union { __hip_bfloat16 h; u16 u; } v; v.h = h; return v.u;
}
__device__ inline float b2f(u16 b) {
  union { u32 u; float f; } v; v.u = ((u32)b) << 16;
  return v.f;
}

// async global->LDS, 16B per lane; LDS dest is wave-uniform base + lane*16
__device__ __forceinline__ void gload16(const u16* g, u16* l) {
  __builtin_amdgcn_global_load_lds(
      (__attribute__((address_space(1))) void*)(g),
      (__attribute__((address_space(3))) void*)(l),
      16, 0, 0);
}

// ---------------- fused prep 1: cast x to bf16 (fat blocks) + both weight transposes ----------------
__global__ __launch_bounds__(256) void k_prep1(const float* __restrict__ x,
                                               const float* __restrict__ Wqkv,
                                               const float* __restrict__ Wo,
                                               u16* __restrict__ xb,
                                               u16* __restrict__ wqkvT,
                                               u16* __restrict__ woT) {
  int idx = blockIdx.x;
  if (idx < 2048) {
    int i = (idx * 256 + threadIdx.x) * 8;
    float4 v0 = *(const float4*)&x[i];
    float4 v1 = *(const float4*)&x[i + 4];
    ushort4 o0, o1;
    o0.x = f2b(v0.x); o0.y = f2b(v0.y); o0.z = f2b(v0.z); o0.w = f2b(v0.w);
    o1.x = f2b(v1.x); o1.y = f2b(v1.y); o1.z = f2b(v1.z); o1.w = f2b(v1.w);
    *(ushort4*)&xb[i]     = o0;
    *(ushort4*)&xb[i + 4] = o1;
    return;
  }
  __shared__ u16 t[32][33];
  const float* W; u16* WT; int K, N, bxi, byi;
  if (idx < 5120) {
    int id2 = idx - 2048;               // 96 x 32
    W = Wqkv; WT = wqkvT; K = 1024; N = 3072;
    bxi = id2 % 96; byi = id2 / 96;
  } else {
    int id2 = idx - 5120;               // 32 x 32
    W = Wo; WT = woT; K = 1024; N = 1024;
    bxi = id2 & 31; byi = id2 >> 5;
  }
  int bx = bxi * 32, by = byi * 32;
  int xx = threadIdx.x & 31, yy = threadIdx.x >> 5;
  for (int j = 0; j < 4; ++j) {
    int r = yy + j * 8;
    t[r][xx] = f2b(W[(size_t)(by + r) * N + bx + xx]);
  }
  __syncthreads();
  for (int j = 0; j < 4; ++j) {
    int r = yy + j * 8;
    WT[(size_t)(bx + r) * K + by + xx] = t[xx][r];
  }
}

// ---------------- GEMM 128x128 with XOR-swizzled LDS (proven R13 form) — GEMM1 ----------------
template <bool F32OUT>
__global__ __launch_bounds__(256) void k_gemm(const u16* __restrict__ A,
                                              const u16* __restrict__ Bt,
                                              void* __restrict__ Cout,
                                              int M, int N, int K) {
  __shared__ u16 As[2][128 * 64];
  __shared__ u16 Bs[2][128 * 64];
  const int tid = threadIdx.x;
  const int lane = tid & 63, wid = tid >> 6;
  const int l15 = lane & 15, lg = lane >> 4;
  const int bm = blockIdx.x * 128, bn = blockIdx.y * 128;
  const int wr = (wid >> 1) * 64, wc = (wid & 1) * 64;

  f4 acc[4][4] = {};

  const int srow = wid * 32 + (lane >> 3);
  const int scol = ((lane & 7) ^ ((lane >> 3) & 7)) * 8;
  const u16* gA = A  + (size_t)(bm + srow) * K + scol;
  const u16* gB = Bt + (size_t)(bn + srow) * K + scol;

  const int nk = K >> 6;

  {
    const u16* ga = gA; const u16* gb = gB;
    u16* la = &As[0][(wid * 32) * 64];
    u16* lb = &Bs[0][(wid * 32) * 64];
    #pragma unroll
    for (int c = 0; c < 4; ++c) {
      gload16(ga, la);
      gload16(gb, lb);
      ga += (size_t)8 * K; gb += (size_t)8 * K;
      la += 8 * 64;        lb += 8 * 64;
    }
  }
  __syncthreads();

  for (int t = 0; t < nk; ++t) {
    if (t + 1 < nk) {
      int kb = (t + 1) << 6;
      const u16* ga = gA + kb; const u16* gb = gB + kb;
      u16* la = &As[(t + 1) & 1][(wid * 32) * 64];
      u16* lb = &Bs[(t + 1) & 1][(wid * 32) * 64];
      #pragma unroll
      for (int c = 0; c < 4; ++c) {
        gload16(ga, la);
        gload16(gb, lb);
        ga += (size_t)8 * K; gb += (size_t)8 * K;
        la += 8 * 64;        lb += 8 * 64;
      }
    }
    const u16* as = &As[t & 1][0];
    const u16* bs = &Bs[t & 1][0];
    #pragma unroll
    for (int kk = 0; kk < 2; ++kk) {
      bh8 a[4], b[4];
      #pragma unroll
      for (int m = 0; m < 4; ++m)
        a[m] = *(const bh8*)&as[(wr + m * 16 + l15) * 64 + (((kk * 4 + lg) ^ (l15 & 7)) * 8)];
      #pragma unroll
      for (int n = 0; n < 4; ++n)
        b[n] = *(const bh8*)&bs[(wc + n * 16 + l15) * 64 + (((kk * 4 + lg) ^ (l15 & 7)) * 8)];
      #pragma unroll
      for (int m = 0; m < 4; ++m)
        #pragma unroll
        for (int n = 0; n < 4; ++n)
          acc[m][n] = __builtin_amdgcn_mfma_f32_16x16x32_bf16(a[m], b[n], acc[m][n], 0, 0, 0);
    }
    __syncthreads();
  }

  for (int m = 0; m < 4; ++m)
    for (int n = 0; n < 4; ++n)
      for (int r = 0; r < 4; ++r) {
        int row = bm + wr + m * 16 + lg * 4 + r;
        int col = bn + wc + n * 16 + l15;
        float v = acc[m][n][r];
        if constexpr (F32OUT) ((float*)Cout)[(size_t)row * N + col] = v;
        else                  ((u16*)Cout)[(size_t)row * N + col]  = f2b(v);
      }
}

// ---------------- GEMM2: 64x128 tile, same staging/swizzle skeleton; 512 blocks, 8 waves/CU ----------------
__global__ __launch_bounds__(256) void k_gemm64(const u16* __restrict__ A,
                                                const u16* __restrict__ Bt,
                                                float* __restrict__ Cout,
                                                int M, int N, int K) {
  __shared__ u16 As[2][64 * 64];    // 16 KB
  __shared__ u16 Bs[2][128 * 64];   // 32 KB
  const int tid = threadIdx.x;
  const int lane = tid & 63, wid = tid >> 6;
  const int l15 = lane & 15, lg = lane >> 4;
  const int bm = blockIdx.x * 64, bn = blockIdx.y * 128;
  const int wr = (wid >> 1) * 32, wc = (wid & 1) * 64;

  f4 acc[2][4] = {};

  // staging: wave stages A rows [wid*16, +16) (2 gloads) and B rows [wid*32, +32) (4 gloads)
  const int arow = wid * 16 + (lane >> 3);
  const int brow = wid * 32 + (lane >> 3);
  const int scol = ((lane & 7) ^ ((lane >> 3) & 7)) * 8;   // all staged rows ≡ (lane>>3) mod 8
  const u16* gA = A  + (size_t)(bm + arow) * K + scol;
  const u16* gB = Bt + (size_t)(bn + brow) * K + scol;

  const int nk = K >> 6;

#define STAGE64(T)                                                 \
  {                                                                \
    int kb_ = (T) << 6; int bf_ = (T) & 1;                         \
    u16* la = &As[bf_][(wid * 16) * 64];                           \
    gload16(gA + kb_, la);                                         \
    gload16(gA + kb_ + (size_t)8 * K, la + 8 * 64);                \
    u16* lb = &Bs[bf_][(wid * 32) * 64];                           \
    const u16* gb = gB + kb_;                                      \
    _Pragma("unroll")                                              \
    for (int c = 0; c < 4; ++c) {                                  \
      gload16(gb, lb);                                             \
      gb += (size_t)8 * K; lb += 8 * 64;                           \
    }                                                              \
  }

  STAGE64(0);
  __syncthreads();

  for (int t = 0; t < nk; ++t) {
    if (t + 1 < nk) STAGE64(t + 1);
    const u16* as = &As[t & 1][0];
    const u16* bs = &Bs[t & 1][0];
    #pragma unroll
    for (int kk = 0; kk < 2; ++kk) {
      bh8 a[2], b[4];
      #pragma unroll
      for (int m = 0; m < 2; ++m)
        a[m] = *(const bh8*)&as[(wr + m * 16 + l15) * 64 + (((kk * 4 + lg) ^ (l15 & 7)) * 8)];
      #pragma unroll
      for (int n = 0; n < 4; ++n)
        b[n] = *(const bh8*)&bs[(wc + n * 16 + l15) * 64 + (((kk * 4 + lg) ^ (l15 & 7)) * 8)];
      #pragma unroll
      for (int m = 0; m < 2; ++m)
        #pragma unroll
        for (int n = 0; n < 4; ++n)
          acc[m][n] = __builtin_amdgcn_mfma_f32_16x16x32_bf16(a[m], b[n], acc[m][n], 0, 0, 0);
    }
    __syncthreads();
  }
#undef STAGE64

  for (int m = 0; m < 2; ++m)
    for (int n = 0; n < 4; ++n)
      for (int r = 0; r < 4; ++r) {
        int row = bm + wr + m * 16 + lg * 4 + r;
        int col = bn + wc + n * 16 + l15;
        Cout[(size_t)row * N + col] = acc[m][n][r];
      }
}

// ---------------- fused prep 2: vectorized RMSNorm+RoPE (Q,K) + vectorized V transpose ----------------
__global__ __launch_bounds__(256) void k_prep2(const u16* __restrict__ qkv,
                                               const float* __restrict__ qw,
                                               const float* __restrict__ kw,
                                               const float* __restrict__ cosp,
                                               const float* __restrict__ sinp,
                                               u16* __restrict__ Q,
                                               u16* __restrict__ K,
                                               u16* __restrict__ Vt) {
  const float CSC = 0.125f * 1.44269504088896f;
  int idx = blockIdx.x;
  if (idx < 2048) {
    int wid = threadIdx.x >> 6, lane = threadIdx.x & 63;
    int gw = idx * 4 + wid;
    int isK = gw & 1;
    int bl = gw >> 1;
    int l = bl & 2047, b = bl >> 11;
    int h = lane >> 2, qd = lane & 3;
    const u16* src = qkv + (size_t)bl * 3072 + isK * 1024 + h * 64 + qd * 8;
    bh8 t1 = *(const bh8*)src;
    bh8 t2 = *(const bh8*)(src + 32);
    float a1[8], a2[8];
    float ss = 0.0f;
    #pragma unroll
    for (int j = 0; j < 8; ++j) {
      a1[j] = b2f((u16)t1[j]); a2[j] = b2f((u16)t2[j]);
      ss += a1[j] * a1[j] + a2[j] * a2[j];
    }
    ss += __shfl_xor(ss, 1, 64);
    ss += __shfl_xor(ss, 2, 64);
    float rr = rsqrtf(ss * (1.0f / 64.0f) + 1e-6f);
    const float* wt = isK ? kw : qw;
    float w1[8], w2[8], cc[8], sn[8];
    *(float4*)&w1[0] = *(const float4*)&wt[qd * 8];
    *(float4*)&w1[4] = *(const float4*)&wt[qd * 8 + 4];
    *(float4*)&w2[0] = *(const float4*)&wt[32 + qd * 8];
    *(float4*)&w2[4] = *(const float4*)&wt[32 + qd * 8 + 4];
    *(float4*)&cc[0] = *(const float4*)&cosp[l * 32 + qd * 8];
    *(float4*)&cc[4] = *(const float4*)&cosp[l * 32 + qd * 8 + 4];
    *(float4*)&sn[0] = *(const float4*)&sinp[l * 32 + qd * 8];
    *(float4*)&sn[4] = *(const float4*)&sinp[l * 32 + qd * 8 + 4];
    float scl = isK ? 1.0f : CSC;
    bh8 o1, o2;
    #pragma unroll
    for (int j = 0; j < 8; ++j) {
      float x1 = a1[j] * rr * w1[j];
      float x2 = a2[j] * rr * w2[j];
      o1[j] = (short)f2b((x1 * cc[j] - x2 * sn[j]) * scl);
      o2[j] = (short)f2b((x1 * sn[j] + x2 * cc[j]) * scl);
    }
    u16* dst = (isK ? K : Q) + ((size_t)(b * 16 + h) * 2048 + l) * 64 + qd * 8;
    *(bh8*)dst = o1;
    *(bh8*)(dst + 32) = o2;
  } else {
    // vectorized V transpose: [64 l][64 d] tile per block, bh8 on both global sides
    __shared__ u16 tt[64][66];
    int v = idx - 2048;                 // 0..1023: bh (32) x l-tile (32)
    int bh = v >> 5, lt = v & 31;
    int b = bh >> 4, h = bh & 15;
    int lb = lt * 64;
    const u16* src = qkv + (size_t)b * 2048 * 3072 + 2048 + h * 64;
    int r0 = threadIdx.x >> 3, c0 = (threadIdx.x & 7) * 8;
    *(bh8*)&tt[r0][c0]      = *(const bh8*)&src[(size_t)(lb + r0) * 3072 + c0];
    *(bh8*)&tt[r0 + 32][c0] = *(const bh8*)&src[(size_t)(lb + r0 + 32) * 3072 + c0];
    __syncthreads();
    u16* dst = Vt + (size_t)bh * 64 * 2048;
    int d0 = threadIdx.x >> 3, l0 = (threadIdx.x & 7) * 8;
    bh8 o0, o1;
    #pragma unroll
    for (int j = 0; j < 8; ++j) {
      o0[j] = (short)tt[l0 + j][d0];
      o1[j] = (short)tt[l0 + j][d0 + 32];
    }
    *(bh8*)&dst[(size_t)d0 * 2048 + lb + l0]        = o0;
    *(bh8*)&dst[(size_t)(d0 + 32) * 2048 + lb + l0] = o1;
  }
}

// ---------------- flash attention, causal; R17 proven best (XCD-grouped bh, defer-max) ----------------
__global__ __launch_bounds__(256, 3) void k_attn(const u16* __restrict__ Q,
                                                 const u16* __restrict__ K,
                                                 const u16* __restrict__ Vt,
                                                 u16* __restrict__ O,
                                                 u16* __restrict__ Opart,
                                                 float2* __restrict__ Ml) {
  __shared__ u16 Ks[2][64 * 64];   // [k-local][d], XOR-swizzled chunks
  __shared__ u16 Vs[2][64 * 64];   // [d][k-local], XOR-swizzled chunks
  __shared__ u16 Pl[4][32][64];    // per-wave P, XOR-swizzled 16B chunks

  const int wid = threadIdx.x >> 6, lane = threadIdx.x & 63;
  const int l15 = lane & 15, lg = lane >> 4;

  // XCD-grouped block remap (1472 = 8 XCD * 4 bh * 46 chunks)
  const int linear = (int)blockIdx.y * 46 + (int)blockIdx.x;
  const int xcd = linear & 7;
  const int rest = linear >> 3;
  const int bh = xcd * 4 + (rest & 3);
  const int chunkIdx = rest >> 2;          // 0..45; chunk 0 of all bh dispatch first
  const int b = bh >> 4, h = bh & 15;

  const int ctab[17] = {0,1,2,3,5,7,9,11,14,17,20,24,28,32,36,41,46};
  const int id = 45 - chunkIdx;            // longest chunks first
  int qt = 0;
  #pragma unroll
  for (int qq = 0; qq < 16; ++qq)
    if (id >= ctab[qq + 1]) qt = qq + 1;
  const int part = id - ctab[qt];
  const int ways = ctab[qt + 1] - ctab[qt];
  const int T = 2 * qt + 2;
  const int t0 = part * T / ways;
  const int t1 = (part + 1) * T / ways;
  const int slot = (ways == 1) ? -1 : bh * 43 + (id - 3);

  const int qb = qt * 128 + wid * 32;

  const u16* Qp = Q  + (size_t)bh * 2048 * 64;
  const u16* Kp = K  + (size_t)bh * 2048 * 64;
  const u16* Vp = Vt + (size_t)bh * 64 * 2048;

  const int sr0 = wid * 8 + (lane >> 3);
  const int sc  = lane & 7;

  bh8 aq[2][2];
  #pragma unroll
  for (int qi = 0; qi < 2; ++qi)
    #pragma unroll
    for (int hh = 0; hh < 2; ++hh)
      aq[qi][hh] = *(const bh8*)&Qp[(size_t)(qb + qi * 16 + l15) * 64 + hh * 32 + lg * 8];

  bh8 ones;
  #pragma unroll
  for (int j = 0; j < 8; ++j) ones[j] = (short)0x3F80;

  f4 acc[2][4] = {};
  float mrow[2] = {-1e30f, -1e30f};   // log2 domain
  float lrow[2] = {0.0f, 0.0f};

  const int tmax = (qb + 31) >> 6;

  // prologue: stage tile t0
  {
    int kb0 = t0 * 64;
    int r0 = sr0, r1 = 32 + sr0;
    gload16(Kp + (size_t)(kb0 + r0) * 64 + (size_t)((sc ^ (r0 & 7)) * 8), &Ks[t0 & 1][(wid * 8) * 64]);
    gload16(Kp + (size_t)(kb0 + r1) * 64 + (size_t)((sc ^ (r1 & 7)) * 8), &Ks[t0 & 1][(32 + wid * 8) * 64]);
    gload16(Vp + (size_t)r0 * 2048 + kb0 + (size_t)((sc ^ (r0 & 7)) * 8), &Vs[t0 & 1][(wid * 8) * 64]);
    gload16(Vp + (size_t)r1 * 2048 + kb0 + (size_t)((sc ^ (r1 & 7)) * 8), &Vs[t0 & 1][(32 + wid * 8) * 64]);
  }
  __syncthreads();

  for (int t = t0; t < t1; ++t) {
    if (t + 1 < t1) {
      int kb = (t + 1) * 64;
      int nb = (t + 1) & 1;
      int r0 = sr0, r1 = 32 + sr0;
      gload16(Kp + (size_t)(kb + r0) * 64 + (size_t)((sc ^ (r0 & 7)) * 8), &Ks[nb][(wid * 8) * 64]);
      gload16(Kp + (size_t)(kb + r1) * 64 + (size_t)((sc ^ (r1 & 7)) * 8), &Ks[nb][(32 + wid * 8) * 64]);
      gload16(Vp + (size_t)r0 * 2048 + kb + (size_t)((sc ^ (r0 & 7)) * 8), &Vs[nb][(wid * 8) * 64]);
      gload16(Vp + (size_t)r1 * 2048 + kb + (size_t)((sc ^ (r1 & 7)) * 8), &Vs[nb][(32 + wid * 8) * 64]);
    }
    if (t <= tmax) {
      const int kb = t * 64;
      const bool masked = (t == tmax);
      const u16* ks = &Ks[t & 1][0];
      const u16* vs = &Vs[t & 1][0];

      // ---- QK^T (swapped): D col=q; Q pre-scaled (log2 domain) ----
      f4 sc4[4][2] = {};
      __builtin_amdgcn_s_setprio(1);
      #pragma unroll
      for (int kq = 0; kq < 4; ++kq) {
        int row = kq * 16 + l15;
        int cs = row & 7;
        bh8 ka0 = *(const bh8*)&ks[row * 64 + ((0 + lg) ^ cs) * 8];
        bh8 ka1 = *(const bh8*)&ks[row * 64 + ((4 + lg) ^ cs) * 8];
        #pragma unroll
        for (int qi = 0; qi < 2; ++qi) {
          sc4[kq][qi] = __builtin_amdgcn_mfma_f32_16x16x32_bf16(ka0, aq[qi][0], sc4[kq][qi], 0, 0, 0);
          sc4[kq][qi] = __builtin_amdgcn_mfma_f32_16x16x32_bf16(ka1, aq[qi][1], sc4[kq][qi], 0, 0, 0);
        }
      }
      __builtin_amdgcn_s_setprio(0);

      // ---- online softmax (log2 domain), defer-max THR=8, mask only diag ----
      #pragma unroll
      for (int qi = 0; qi < 2; ++qi) {
        if (masked) {
          int q = qb + qi * 16 + l15;
          #pragma unroll
          for (int kq = 0; kq < 4; ++kq)
            #pragma unroll
            for (int r = 0; r < 4; ++r)
              if (kb + kq * 16 + lg * 4 + r > q) sc4[kq][qi][r] = -1e30f;
        }
        float mx = -1e30f;
        #pragma unroll
        for (int kq = 0; kq < 4; ++kq)
          #pragma unroll
          for (int r = 0; r < 4; ++r)
            mx = fmaxf(mx, sc4[kq][qi][r]);
        mx = fmaxf(mx, __shfl_xor(mx, 16, 64));
        mx = fmaxf(mx, __shfl_xor(mx, 32, 64));
        if (__any(mx > mrow[qi] + 8.0f)) {
          float mnew = fmaxf(mrow[qi], mx);
          float fac = exp2f(mrow[qi] - mnew);
          mrow[qi] = mnew;
          lrow[qi] *= fac;
          #pragma unroll
          for (int n = 0; n < 4; ++n)
            #pragma unroll
            for (int r = 0; r < 4; ++r) acc[qi][n][r] *= fac;
        }
        #pragma unroll
        for (int kq = 0; kq < 4; ++kq)
          #pragma unroll
          for (int r = 0; r < 4; ++r)
            sc4[kq][qi][r] = exp2f(sc4[kq][qi][r] - mrow[qi]);
      }

      // ---- P -> per-wave LDS (XOR-swizzled 16B chunks; DS pipe) ----
      char* plb = (char*)&Pl[wid][0][0];
      #pragma unroll
      for (int qi = 0; qi < 2; ++qi) {
        int row = qi * 16 + l15;
        #pragma unroll
        for (int kq = 0; kq < 4; ++kq) {
          ushort4 w4;
          w4.x = f2b(sc4[kq][qi][0]); w4.y = f2b(sc4[kq][qi][1]);
          w4.z = f2b(sc4[kq][qi][2]); w4.w = f2b(sc4[kq][qi][3]);
          int ch = (kq * 2 + (lg >> 1)) ^ (row & 7);
          *(ushort4*)(plb + row * 128 + ch * 16 + (lg & 1) * 8) = w4;
        }
      }
      asm volatile("s_waitcnt lgkmcnt(0)" ::: "memory");
      __builtin_amdgcn_sched_barrier(0);

      // ---- PV (double-swapped) + row-sum via ones-MFMA ----
      f4 sum0 = {}, sum1 = {};
      __builtin_amdgcn_s_setprio(1);
      #pragma unroll
      for (int g = 0; g < 2; ++g) {
        bh8 pb0 = *(const bh8*)(plb + l15 * 128 + (((g * 4 + lg) ^ (l15 & 7)) * 16));
        bh8 pb1 = *(const bh8*)(plb + (16 + l15) * 128 + (((g * 4 + lg) ^ (l15 & 7)) * 16));
        #pragma unroll
        for (int n = 0; n < 4; ++n) {
          int row = n * 16 + l15;
          bh8 va = *(const bh8*)&vs[row * 64 + (((g * 4 + lg) ^ (row & 7)) * 8)];
          acc[0][n] = __builtin_amdgcn_mfma_f32_16x16x32_bf16(va, pb0, acc[0][n], 0, 0, 0);
          acc[1][n] = __builtin_amdgcn_mfma_f32_16x16x32_bf16(va, pb1, acc[1][n], 0, 0, 0);
        }
        sum0 = __builtin_amdgcn_mfma_f32_16x16x32_bf16(ones, pb0, sum0, 0, 0, 0);
        sum1 = __builtin_amdgcn_mfma_f32_16x16x32_bf16(ones, pb1, sum1, 0, 0, 0);
      }
      __builtin_amdgcn_s_setprio(0);
      lrow[0] += sum0[0];
      lrow[1] += sum1[0];
    }
    __syncthreads();
  }

  if (slot < 0) {
    #pragma unroll
    for (int qi = 0; qi < 2; ++qi) {
      float inv = 1.0f / lrow[qi];
      int q = qb + qi * 16 + l15;
      #pragma unroll
      for (int n = 0; n < 4; ++n) {
        ushort4 w4;
        w4.x = f2b(acc[qi][n][0] * inv);
        w4.y = f2b(acc[qi][n][1] * inv);
        w4.z = f2b(acc[qi][n][2] * inv);
        w4.w = f2b(acc[qi][n][3] * inv);
        *(ushort4*)&O[((size_t)b * 2048 + q) * 1024 + h * 64 + n * 16 + lg * 4] = w4;
      }
    }
  } else {
    u16* op = Opart + (size_t)slot * 8192;
    #pragma unroll
    for (int qi = 0; qi < 2; ++qi) {
      int rloc = wid * 32 + qi * 16 + l15;
      #pragma unroll
      for (int n = 0; n < 4; ++n) {
        ushort4 w4;
        w4.x = f2b(acc[qi][n][0]); w4.y = f2b(acc[qi][n][1]);
        w4.z = f2b(acc[qi][n][2]); w4.w = f2b(acc[qi][n][3]);
        *(ushort4*)&op[(size_t)rloc * 64 + n * 16 + lg * 4] = w4;
      }
      if (lg == 0) Ml[slot * 128 + rloc] = make_float2(mrow[qi], lrow[qi]);
    }
  }
}

// ---------------- combine split-K partials (2..5-way, 128-row slots) ----------------
__global__ __launch_bounds__(256) void k_comb(const u16* __restrict__ Opart,
                                              const float2* __restrict__ Ml,
                                              u16* __restrict__ O) {
  const int ctab[17] = {0,1,2,3,5,7,9,11,14,17,20,24,28,32,36,41,46};
  int qt = 3 + (int)blockIdx.x;     // 3..15
  int bh = blockIdx.y;
  int b = bh >> 4, h = bh & 15;
  int ways = ctab[qt + 1] - ctab[qt];
  int base = bh * 43 + ctab[qt] - 3;
  int row = threadIdx.x >> 1;
  int db  = (threadIdx.x & 1) * 32;

  float2 ml[5]; float wgt[5];
  float M = -1e30f;
  #pragma unroll
  for (int w = 0; w < 5; ++w)
    if (w < ways) { ml[w] = Ml[(base + w) * 128 + row]; M = fmaxf(M, ml[w].x); }
  float l = 0.0f;
  #pragma unroll
  for (int w = 0; w < 5; ++w)
    if (w < ways) { wgt[w] = exp2f(ml[w].x - M); l += wgt[w] * ml[w].y; }
  float inv = 1.0f / l;

  u16* dst = O + ((size_t)b * 2048 + qt * 128 + row) * 1024 + h * 64 + db;
  #pragma unroll
  for (int j = 0; j < 32; j += 8) {
    float a[8] = {};
    #pragma unroll
    for (int w = 0; w < 5; ++w)
      if (w < ways) {
        bh8 v = *(const bh8*)&Opart[(size_t)(base + w) * 8192 + (size_t)row * 64 + db + j];
        #pragma unroll
        for (int e = 0; e < 8; ++e) a[e] += wgt[w] * b2f((u16)v[e]);
      }
    bh8 o;
    #pragma unroll
    for (int e = 0; e < 8; ++e) o[e] = (short)f2b(a[e] * inv);
    *(bh8*)&dst[j] = o;
  }
}

extern "C" void kernel_launch(void* const* d_in, const int* in_sizes, int n_in,
                              void* d_out, int out_size, void* d_ws, size_t ws_size,
                              hipStream_t stream) {
  (void)in_sizes; (void)n_in; (void)out_size; (void)ws_size;
  const float* x    = (const float*)d_in[0];
  const float* Wqkv = (const float*)d_in[1];
  const float* Wo   = (const float*)d_in[2];
  const float* qw   = (const float*)d_in[3];
  const float* kw   = (const float*)d_in[4];
  const float* cosp = (const float*)d_in[5];
  const float* sinp = (const float*)d_in[6];
  float* out = (float*)d_out;

  char* ws = (char*)d_ws;
  u16* xb    = (u16*)(ws);                 //  8,388,608 B  x bf16 [4096][1024]
  u16* wqkvT = (u16*)(ws + 8388608);       //  6,291,456 B  Wqkv^T bf16
  u16* woT   = (u16*)(ws + 14680064);      //  2,097,152 B  Wo^T bf16
  u16* qkv   = (u16*)(ws + 16777216);      // 25,165,824 B  qkv bf16 [4096][3072]
  u16* Qb    = (u16*)(ws + 41943040);      //  8,388,608 B  [B,H,L,D]
  u16* Kb    = (u16*)(ws + 50331648);      //  8,388,608 B
  u16* Vtb   = (u16*)(ws + 58720256);      //  8,388,608 B  [B,H,D,L]
  u16* AO    = (u16*)(ws + 67108864);      //  8,388,608 B  attn_out bf16
  // split-K partials overlay the dead qkv region:
  // 1376 slots * 8192 u16 * 2B = 22,544,384 B; Ml after it (1,409,024 B); total < 25,165,824 B
  u16*    Opart = (u16*)(ws + 16777216);
  float2* Mlb   = (float2*)(ws + 16777216 + 22544384);

  k_prep1<<<6144, 256, 0, stream>>>(x, Wqkv, Wo, xb, wqkvT, woT);
  k_gemm<false><<<dim3(32, 24), 256, 0, stream>>>(xb, wqkvT, qkv, 4096, 3072, 1024);
  k_prep2<<<3072, 256, 0, stream>>>(qkv, qw, kw, cosp, sinp, Qb, Kb, Vtb);
  k_attn<<<dim3(46, 32), 256, 0, stream>>>(Qb, Kb, Vtb, AO, Opart, Mlb);
  k_comb<<<dim3(13, 32), 256, 0, stream>>>(Opart, Mlb, AO);
  k_gemm64<<<dim3(64, 8), 256, 0, stream>>>(AO, woT, out, 4096, 1024, 1024);
}

// Round 27
// 129.196 us; speedup vs baseline: 1.0524x; 1.0336x over previous
//
#include <hip/hip_runtime.h>
#include <hip/hip_bf16.h>

typedef __attribute__((ext_vector_type(8))) short bh8;   // 8 bf16 in 4 VGPRs
typedef __attribute__((ext_vector_type(4))) float f4;    // MFMA accumulator

typedef unsigned short u16;
typedef unsigned int u32;

__device__ inline u16 f2b(float f) {
  __hip_bfloat16 h = __float2bfloat16(f);
  union { __hip_bfloat16 h; u16 u; } v; v.h = h; return v.u;
}
__device__ inline float b2f(u16 b) {
  union { u32 u; float f; } v; v.u = ((u32)b) << 16;
  return v.f;
}

// async global->LDS, 16B per lane; LDS dest is wave-uniform base + lane*16
__device__ __forceinline__ void gload16(const u16* g, u16* l) {
  __builtin_amdgcn_global_load_lds(
      (__attribute__((address_space(1))) void*)(g),
      (__attribute__((address_space(3))) void*)(l),
      16, 0, 0);
}

// ---------------- fused prep 1: cast x to bf16 (fat blocks) + both weight transposes ----------------
__global__ __launch_bounds__(256) void k_prep1(const float* __restrict__ x,
                                               const float* __restrict__ Wqkv,
                                               const float* __restrict__ Wo,
                                               u16* __restrict__ xb,
                                               u16* __restrict__ wqkvT,
                                               u16* __restrict__ woT) {
  int idx = blockIdx.x;
  if (idx < 2048) {
    int i = (idx * 256 + threadIdx.x) * 8;
    float4 v0 = *(const float4*)&x[i];
    float4 v1 = *(const float4*)&x[i + 4];
    ushort4 o0, o1;
    o0.x = f2b(v0.x); o0.y = f2b(v0.y); o0.z = f2b(v0.z); o0.w = f2b(v0.w);
    o1.x = f2b(v1.x); o1.y = f2b(v1.y); o1.z = f2b(v1.z); o1.w = f2b(v1.w);
    *(ushort4*)&xb[i]     = o0;
    *(ushort4*)&xb[i + 4] = o1;
    return;
  }
  __shared__ u16 t[32][33];
  const float* W; u16* WT; int K, N, bxi, byi;
  if (idx < 5120) {
    int id2 = idx - 2048;               // 96 x 32
    W = Wqkv; WT = wqkvT; K = 1024; N = 3072;
    bxi = id2 % 96; byi = id2 / 96;
  } else {
    int id2 = idx - 5120;               // 32 x 32
    W = Wo; WT = woT; K = 1024; N = 1024;
    bxi = id2 & 31; byi = id2 >> 5;
  }
  int bx = bxi * 32, by = byi * 32;
  int xx = threadIdx.x & 31, yy = threadIdx.x >> 5;
  for (int j = 0; j < 4; ++j) {
    int r = yy + j * 8;
    t[r][xx] = f2b(W[(size_t)(by + r) * N + bx + xx]);
  }
  __syncthreads();
  for (int j = 0; j < 4; ++j) {
    int r = yy + j * 8;
    WT[(size_t)(bx + r) * K + by + xx] = t[xx][r];
  }
}

// ---------------- GEMM 64x128 tile, XOR-swizzled LDS (proven R24 skeleton), both GEMMs ----------------
// 48 KB LDS -> 3 blocks/CU (12 waves/CU). GEMM1: grid (64,24)=1536 blocks = 2 even
// occupancy rounds (fixes the 128^2 kernel's 1.5-round tail). GEMM2: grid (64,8).
template <bool F32OUT>
__global__ __launch_bounds__(256) void k_gemm64(const u16* __restrict__ A,
                                                const u16* __restrict__ Bt,
                                                void* __restrict__ Cout,
                                                int M, int N, int K) {
  __shared__ u16 As[2][64 * 64];    // 16 KB
  __shared__ u16 Bs[2][128 * 64];   // 32 KB
  const int tid = threadIdx.x;
  const int lane = tid & 63, wid = tid >> 6;
  const int l15 = lane & 15, lg = lane >> 4;
  const int bm = blockIdx.x * 64, bn = blockIdx.y * 128;
  const int wr = (wid >> 1) * 32, wc = (wid & 1) * 64;

  f4 acc[2][4] = {};

  // staging: wave stages A rows [wid*16, +16) (2 gloads) and B rows [wid*32, +32) (4 gloads)
  const int arow = wid * 16 + (lane >> 3);
  const int brow = wid * 32 + (lane >> 3);
  const int scol = ((lane & 7) ^ ((lane >> 3) & 7)) * 8;   // all staged rows ≡ (lane>>3) mod 8
  const u16* gA = A  + (size_t)(bm + arow) * K + scol;
  const u16* gB = Bt + (size_t)(bn + brow) * K + scol;

  const int nk = K >> 6;

#define STAGE64(T)                                                 \
  {                                                                \
    int kb_ = (T) << 6; int bf_ = (T) & 1;                         \
    u16* la = &As[bf_][(wid * 16) * 64];                           \
    gload16(gA + kb_, la);                                         \
    gload16(gA + kb_ + (size_t)8 * K, la + 8 * 64);                \
    u16* lb = &Bs[bf_][(wid * 32) * 64];                           \
    const u16* gb = gB + kb_;                                      \
    _Pragma("unroll")                                              \
    for (int c = 0; c < 4; ++c) {                                  \
      gload16(gb, lb);                                             \
      gb += (size_t)8 * K; lb += 8 * 64;                           \
    }                                                              \
  }

  STAGE64(0);
  __syncthreads();

  for (int t = 0; t < nk; ++t) {
    if (t + 1 < nk) STAGE64(t + 1);
    const u16* as = &As[t & 1][0];
    const u16* bs = &Bs[t & 1][0];
    #pragma unroll
    for (int kk = 0; kk < 2; ++kk) {
      bh8 a[2], b[4];
      #pragma unroll
      for (int m = 0; m < 2; ++m)
        a[m] = *(const bh8*)&as[(wr + m * 16 + l15) * 64 + (((kk * 4 + lg) ^ (l15 & 7)) * 8)];
      #pragma unroll
      for (int n = 0; n < 4; ++n)
        b[n] = *(const bh8*)&bs[(wc + n * 16 + l15) * 64 + (((kk * 4 + lg) ^ (l15 & 7)) * 8)];
      #pragma unroll
      for (int m = 0; m < 2; ++m)
        #pragma unroll
        for (int n = 0; n < 4; ++n)
          acc[m][n] = __builtin_amdgcn_mfma_f32_16x16x32_bf16(a[m], b[n], acc[m][n], 0, 0, 0);
    }
    __syncthreads();
  }
#undef STAGE64

  for (int m = 0; m < 2; ++m)
    for (int n = 0; n < 4; ++n)
      for (int r = 0; r < 4; ++r) {
        int row = bm + wr + m * 16 + lg * 4 + r;
        int col = bn + wc + n * 16 + l15;
        float v = acc[m][n][r];
        if constexpr (F32OUT) ((float*)Cout)[(size_t)row * N + col] = v;
        else                  ((u16*)Cout)[(size_t)row * N + col]  = f2b(v);
      }
}

// ---------------- fused prep 2: vectorized RMSNorm+RoPE (Q,K) + vectorized V transpose ----------------
__global__ __launch_bounds__(256) void k_prep2(const u16* __restrict__ qkv,
                                               const float* __restrict__ qw,
                                               const float* __restrict__ kw,
                                               const float* __restrict__ cosp,
                                               const float* __restrict__ sinp,
                                               u16* __restrict__ Q,
                                               u16* __restrict__ K,
                                               u16* __restrict__ Vt) {
  const float CSC = 0.125f * 1.44269504088896f;
  int idx = blockIdx.x;
  if (idx < 2048) {
    int wid = threadIdx.x >> 6, lane = threadIdx.x & 63;
    int gw = idx * 4 + wid;
    int isK = gw & 1;
    int bl = gw >> 1;
    int l = bl & 2047, b = bl >> 11;
    int h = lane >> 2, qd = lane & 3;
    const u16* src = qkv + (size_t)bl * 3072 + isK * 1024 + h * 64 + qd * 8;
    bh8 t1 = *(const bh8*)src;
    bh8 t2 = *(const bh8*)(src + 32);
    float a1[8], a2[8];
    float ss = 0.0f;
    #pragma unroll
    for (int j = 0; j < 8; ++j) {
      a1[j] = b2f((u16)t1[j]); a2[j] = b2f((u16)t2[j]);
      ss += a1[j] * a1[j] + a2[j] * a2[j];
    }
    ss += __shfl_xor(ss, 1, 64);
    ss += __shfl_xor(ss, 2, 64);
    float rr = rsqrtf(ss * (1.0f / 64.0f) + 1e-6f);
    const float* wt = isK ? kw : qw;
    float w1[8], w2[8], cc[8], sn[8];
    *(float4*)&w1[0] = *(const float4*)&wt[qd * 8];
    *(float4*)&w1[4] = *(const float4*)&wt[qd * 8 + 4];
    *(float4*)&w2[0] = *(const float4*)&wt[32 + qd * 8];
    *(float4*)&w2[4] = *(const float4*)&wt[32 + qd * 8 + 4];
    *(float4*)&cc[0] = *(const float4*)&cosp[l * 32 + qd * 8];
    *(float4*)&cc[4] = *(const float4*)&cosp[l * 32 + qd * 8 + 4];
    *(float4*)&sn[0] = *(const float4*)&sinp[l * 32 + qd * 8];
    *(float4*)&sn[4] = *(const float4*)&sinp[l * 32 + qd * 8 + 4];
    float scl = isK ? 1.0f : CSC;
    bh8 o1, o2;
    #pragma unroll
    for (int j = 0; j < 8; ++j) {
      float x1 = a1[j] * rr * w1[j];
      float x2 = a2[j] * rr * w2[j];
      o1[j] = (short)f2b((x1 * cc[j] - x2 * sn[j]) * scl);
      o2[j] = (short)f2b((x1 * sn[j] + x2 * cc[j]) * scl);
    }
    u16* dst = (isK ? K : Q) + ((size_t)(b * 16 + h) * 2048 + l) * 64 + qd * 8;
    *(bh8*)dst = o1;
    *(bh8*)(dst + 32) = o2;
  } else {
    // vectorized V transpose: [64 l][64 d] tile per block, bh8 on both global sides
    __shared__ u16 tt[64][66];
    int v = idx - 2048;                 // 0..1023: bh (32) x l-tile (32)
    int bh = v >> 5, lt = v & 31;
    int b = bh >> 4, h = bh & 15;
    int lb = lt * 64;
    const u16* src = qkv + (size_t)b * 2048 * 3072 + 2048 + h * 64;
    int r0 = threadIdx.x >> 3, c0 = (threadIdx.x & 7) * 8;
    *(bh8*)&tt[r0][c0]      = *(const bh8*)&src[(size_t)(lb + r0) * 3072 + c0];
    *(bh8*)&tt[r0 + 32][c0] = *(const bh8*)&src[(size_t)(lb + r0 + 32) * 3072 + c0];
    __syncthreads();
    u16* dst = Vt + (size_t)bh * 64 * 2048;
    int d0 = threadIdx.x >> 3, l0 = (threadIdx.x & 7) * 8;
    bh8 o0, o1;
    #pragma unroll
    for (int j = 0; j < 8; ++j) {
      o0[j] = (short)tt[l0 + j][d0];
      o1[j] = (short)tt[l0 + j][d0 + 32];
    }
    *(bh8*)&dst[(size_t)d0 * 2048 + lb + l0]        = o0;
    *(bh8*)&dst[(size_t)(d0 + 32) * 2048 + lb + l0] = o1;
  }
}

// ---------------- flash attention, causal; R17 proven best (XCD-grouped bh, defer-max) ----------------
__global__ __launch_bounds__(256, 3) void k_attn(const u16* __restrict__ Q,
                                                 const u16* __restrict__ K,
                                                 const u16* __restrict__ Vt,
                                                 u16* __restrict__ O,
                                                 u16* __restrict__ Opart,
                                                 float2* __restrict__ Ml) {
  __shared__ u16 Ks[2][64 * 64];   // [k-local][d], XOR-swizzled chunks
  __shared__ u16 Vs[2][64 * 64];   // [d][k-local], XOR-swizzled chunks
  __shared__ u16 Pl[4][32][64];    // per-wave P, XOR-swizzled 16B chunks

  const int wid = threadIdx.x >> 6, lane = threadIdx.x & 63;
  const int l15 = lane & 15, lg = lane >> 4;

  // XCD-grouped block remap (1472 = 8 XCD * 4 bh * 46 chunks)
  const int linear = (int)blockIdx.y * 46 + (int)blockIdx.x;
  const int xcd = linear & 7;
  const int rest = linear >> 3;
  const int bh = xcd * 4 + (rest & 3);
  const int chunkIdx = rest >> 2;          // 0..45; chunk 0 of all bh dispatch first
  const int b = bh >> 4, h = bh & 15;

  const int ctab[17] = {0,1,2,3,5,7,9,11,14,17,20,24,28,32,36,41,46};
  const int id = 45 - chunkIdx;            // longest chunks first
  int qt = 0;
  #pragma unroll
  for (int qq = 0; qq < 16; ++qq)
    if (id >= ctab[qq + 1]) qt = qq + 1;
  const int part = id - ctab[qt];
  const int ways = ctab[qt + 1] - ctab[qt];
  const int T = 2 * qt + 2;
  const int t0 = part * T / ways;
  const int t1 = (part + 1) * T / ways;
  const int slot = (ways == 1) ? -1 : bh * 43 + (id - 3);

  const int qb = qt * 128 + wid * 32;

  const u16* Qp = Q  + (size_t)bh * 2048 * 64;
  const u16* Kp = K  + (size_t)bh * 2048 * 64;
  const u16* Vp = Vt + (size_t)bh * 64 * 2048;

  const int sr0 = wid * 8 + (lane >> 3);
  const int sc  = lane & 7;

  bh8 aq[2][2];
  #pragma unroll
  for (int qi = 0; qi < 2; ++qi)
    #pragma unroll
    for (int hh = 0; hh < 2; ++hh)
      aq[qi][hh] = *(const bh8*)&Qp[(size_t)(qb + qi * 16 + l15) * 64 + hh * 32 + lg * 8];

  bh8 ones;
  #pragma unroll
  for (int j = 0; j < 8; ++j) ones[j] = (short)0x3F80;

  f4 acc[2][4] = {};
  float mrow[2] = {-1e30f, -1e30f};   // log2 domain
  float lrow[2] = {0.0f, 0.0f};

  const int tmax = (qb + 31) >> 6;

  // prologue: stage tile t0
  {
    int kb0 = t0 * 64;
    int r0 = sr0, r1 = 32 + sr0;
    gload16(Kp + (size_t)(kb0 + r0) * 64 + (size_t)((sc ^ (r0 & 7)) * 8), &Ks[t0 & 1][(wid * 8) * 64]);
    gload16(Kp + (size_t)(kb0 + r1) * 64 + (size_t)((sc ^ (r1 & 7)) * 8), &Ks[t0 & 1][(32 + wid * 8) * 64]);
    gload16(Vp + (size_t)r0 * 2048 + kb0 + (size_t)((sc ^ (r0 & 7)) * 8), &Vs[t0 & 1][(wid * 8) * 64]);
    gload16(Vp + (size_t)r1 * 2048 + kb0 + (size_t)((sc ^ (r1 & 7)) * 8), &Vs[t0 & 1][(32 + wid * 8) * 64]);
  }
  __syncthreads();

  for (int t = t0; t < t1; ++t) {
    if (t + 1 < t1) {
      int kb = (t + 1) * 64;
      int nb = (t + 1) & 1;
      int r0 = sr0, r1 = 32 + sr0;
      gload16(Kp + (size_t)(kb + r0) * 64 + (size_t)((sc ^ (r0 & 7)) * 8), &Ks[nb][(wid * 8) * 64]);
      gload16(Kp + (size_t)(kb + r1) * 64 + (size_t)((sc ^ (r1 & 7)) * 8), &Ks[nb][(32 + wid * 8) * 64]);
      gload16(Vp + (size_t)r0 * 2048 + kb + (size_t)((sc ^ (r0 & 7)) * 8), &Vs[nb][(wid * 8) * 64]);
      gload16(Vp + (size_t)r1 * 2048 + kb + (size_t)((sc ^ (r1 & 7)) * 8), &Vs[nb][(32 + wid * 8) * 64]);
    }
    if (t <= tmax) {
      const int kb = t * 64;
      const bool masked = (t == tmax);
      const u16* ks = &Ks[t & 1][0];
      const u16* vs = &Vs[t & 1][0];

      // ---- QK^T (swapped): D col=q; Q pre-scaled (log2 domain) ----
      f4 sc4[4][2] = {};
      __builtin_amdgcn_s_setprio(1);
      #pragma unroll
      for (int kq = 0; kq < 4; ++kq) {
        int row = kq * 16 + l15;
        int cs = row & 7;
        bh8 ka0 = *(const bh8*)&ks[row * 64 + ((0 + lg) ^ cs) * 8];
        bh8 ka1 = *(const bh8*)&ks[row * 64 + ((4 + lg) ^ cs) * 8];
        #pragma unroll
        for (int qi = 0; qi < 2; ++qi) {
          sc4[kq][qi] = __builtin_amdgcn_mfma_f32_16x16x32_bf16(ka0, aq[qi][0], sc4[kq][qi], 0, 0, 0);
          sc4[kq][qi] = __builtin_amdgcn_mfma_f32_16x16x32_bf16(ka1, aq[qi][1], sc4[kq][qi], 0, 0, 0);
        }
      }
      __builtin_amdgcn_s_setprio(0);

      // ---- online softmax (log2 domain), defer-max THR=8, mask only diag ----
      #pragma unroll
      for (int qi = 0; qi < 2; ++qi) {
        if (masked) {
          int q = qb + qi * 16 + l15;
          #pragma unroll
          for (int kq = 0; kq < 4; ++kq)
            #pragma unroll
            for (int r = 0; r < 4; ++r)
              if (kb + kq * 16 + lg * 4 + r > q) sc4[kq][qi][r] = -1e30f;
        }
        float mx = -1e30f;
        #pragma unroll
        for (int kq = 0; kq < 4; ++kq)
          #pragma unroll
          for (int r = 0; r < 4; ++r)
            mx = fmaxf(mx, sc4[kq][qi][r]);
        mx = fmaxf(mx, __shfl_xor(mx, 16, 64));
        mx = fmaxf(mx, __shfl_xor(mx, 32, 64));
        if (__any(mx > mrow[qi] + 8.0f)) {
          float mnew = fmaxf(mrow[qi], mx);
          float fac = exp2f(mrow[qi] - mnew);
          mrow[qi] = mnew;
          lrow[qi] *= fac;
          #pragma unroll
          for (int n = 0; n < 4; ++n)
            #pragma unroll
            for (int r = 0; r < 4; ++r) acc[qi][n][r] *= fac;
        }
        #pragma unroll
        for (int kq = 0; kq < 4; ++kq)
          #pragma unroll
          for (int r = 0; r < 4; ++r)
            sc4[kq][qi][r] = exp2f(sc4[kq][qi][r] - mrow[qi]);
      }

      // ---- P -> per-wave LDS (XOR-swizzled 16B chunks; DS pipe) ----
      char* plb = (char*)&Pl[wid][0][0];
      #pragma unroll
      for (int qi = 0; qi < 2; ++qi) {
        int row = qi * 16 + l15;
        #pragma unroll
        for (int kq = 0; kq < 4; ++kq) {
          ushort4 w4;
          w4.x = f2b(sc4[kq][qi][0]); w4.y = f2b(sc4[kq][qi][1]);
          w4.z = f2b(sc4[kq][qi][2]); w4.w = f2b(sc4[kq][qi][3]);
          int ch = (kq * 2 + (lg >> 1)) ^ (row & 7);
          *(ushort4*)(plb + row * 128 + ch * 16 + (lg & 1) * 8) = w4;
        }
      }
      asm volatile("s_waitcnt lgkmcnt(0)" ::: "memory");
      __builtin_amdgcn_sched_barrier(0);

      // ---- PV (double-swapped) + row-sum via ones-MFMA ----
      f4 sum0 = {}, sum1 = {};
      __builtin_amdgcn_s_setprio(1);
      #pragma unroll
      for (int g = 0; g < 2; ++g) {
        bh8 pb0 = *(const bh8*)(plb + l15 * 128 + (((g * 4 + lg) ^ (l15 & 7)) * 16));
        bh8 pb1 = *(const bh8*)(plb + (16 + l15) * 128 + (((g * 4 + lg) ^ (l15 & 7)) * 16));
        #pragma unroll
        for (int n = 0; n < 4; ++n) {
          int row = n * 16 + l15;
          bh8 va = *(const bh8*)&vs[row * 64 + (((g * 4 + lg) ^ (row & 7)) * 8)];
          acc[0][n] = __builtin_amdgcn_mfma_f32_16x16x32_bf16(va, pb0, acc[0][n], 0, 0, 0);
          acc[1][n] = __builtin_amdgcn_mfma_f32_16x16x32_bf16(va, pb1, acc[1][n], 0, 0, 0);
        }
        sum0 = __builtin_amdgcn_mfma_f32_16x16x32_bf16(ones, pb0, sum0, 0, 0, 0);
        sum1 = __builtin_amdgcn_mfma_f32_16x16x32_bf16(ones, pb1, sum1, 0, 0, 0);
      }
      __builtin_amdgcn_s_setprio(0);
      lrow[0] += sum0[0];
      lrow[1] += sum1[0];
    }
    __syncthreads();
  }

  if (slot < 0) {
    #pragma unroll
    for (int qi = 0; qi < 2; ++qi) {
      float inv = 1.0f / lrow[qi];
      int q = qb + qi * 16 + l15;
      #pragma unroll
      for (int n = 0; n < 4; ++n) {
        ushort4 w4;
        w4.x = f2b(acc[qi][n][0] * inv);
        w4.y = f2b(acc[qi][n][1] * inv);
        w4.z = f2b(acc[qi][n][2] * inv);
        w4.w = f2b(acc[qi][n][3] * inv);
        *(ushort4*)&O[((size_t)b * 2048 + q) * 1024 + h * 64 + n * 16 + lg * 4] = w4;
      }
    }
  } else {
    u16* op = Opart + (size_t)slot * 8192;
    #pragma unroll
    for (int qi = 0; qi < 2; ++qi) {
      int rloc = wid * 32 + qi * 16 + l15;
      #pragma unroll
      for (int n = 0; n < 4; ++n) {
        ushort4 w4;
        w4.x = f2b(acc[qi][n][0]); w4.y = f2b(acc[qi][n][1]);
        w4.z = f2b(acc[qi][n][2]); w4.w = f2b(acc[qi][n][3]);
        *(ushort4*)&op[(size_t)rloc * 64 + n * 16 + lg * 4] = w4;
      }
      if (lg == 0) Ml[slot * 128 + rloc] = make_float2(mrow[qi], lrow[qi]);
    }
  }
}

// ---------------- combine split-K partials (2..5-way, 128-row slots) ----------------
__global__ __launch_bounds__(256) void k_comb(const u16* __restrict__ Opart,
                                              const float2* __restrict__ Ml,
                                              u16* __restrict__ O) {
  const int ctab[17] = {0,1,2,3,5,7,9,11,14,17,20,24,28,32,36,41,46};
  int qt = 3 + (int)blockIdx.x;     // 3..15
  int bh = blockIdx.y;
  int b = bh >> 4, h = bh & 15;
  int ways = ctab[qt + 1] - ctab[qt];
  int base = bh * 43 + ctab[qt] - 3;
  int row = threadIdx.x >> 1;
  int db  = (threadIdx.x & 1) * 32;

  float2 ml[5]; float wgt[5];
  float M = -1e30f;
  #pragma unroll
  for (int w = 0; w < 5; ++w)
    if (w < ways) { ml[w] = Ml[(base + w) * 128 + row]; M = fmaxf(M, ml[w].x); }
  float l = 0.0f;
  #pragma unroll
  for (int w = 0; w < 5; ++w)
    if (w < ways) { wgt[w] = exp2f(ml[w].x - M); l += wgt[w] * ml[w].y; }
  float inv = 1.0f / l;

  u16* dst = O + ((size_t)b * 2048 + qt * 128 + row) * 1024 + h * 64 + db;
  #pragma unroll
  for (int j = 0; j < 32; j += 8) {
    float a[8] = {};
    #pragma unroll
    for (int w = 0; w < 5; ++w)
      if (w < ways) {
        bh8 v = *(const bh8*)&Opart[(size_t)(base + w) * 8192 + (size_t)row * 64 + db + j];
        #pragma unroll
        for (int e = 0; e < 8; ++e) a[e] += wgt[w] * b2f((u16)v[e]);
      }
    bh8 o;
    #pragma unroll
    for (int e = 0; e < 8; ++e) o[e] = (short)f2b(a[e] * inv);
    *(bh8*)&dst[j] = o;
  }
}

extern "C" void kernel_launch(void* const* d_in, const int* in_sizes, int n_in,
                              void* d_out, int out_size, void* d_ws, size_t ws_size,
                              hipStream_t stream) {
  (void)in_sizes; (void)n_in; (void)out_size; (void)ws_size;
  const float* x    = (const float*)d_in[0];
  const float* Wqkv = (const float*)d_in[1];
  const float* Wo   = (const float*)d_in[2];
  const float* qw   = (const float*)d_in[3];
  const float* kw   = (const float*)d_in[4];
  const float* cosp = (const float*)d_in[5];
  const float* sinp = (const float*)d_in[6];
  float* out = (float*)d_out;

  char* ws = (char*)d_ws;
  u16* xb    = (u16*)(ws);                 //  8,388,608 B  x bf16 [4096][1024]
  u16* wqkvT = (u16*)(ws + 8388608);       //  6,291,456 B  Wqkv^T bf16
  u16* woT   = (u16*)(ws + 14680064);      //  2,097,152 B  Wo^T bf16
  u16* qkv   = (u16*)(ws + 16777216);      // 25,165,824 B  qkv bf16 [4096][3072]
  u16* Qb    = (u16*)(ws + 41943040);      //  8,388,608 B  [B,H,L,D]
  u16* Kb    = (u16*)(ws + 50331648);      //  8,388,608 B
  u16* Vtb   = (u16*)(ws + 58720256);      //  8,388,608 B  [B,H,D,L]
  u16* AO    = (u16*)(ws + 67108864);      //  8,388,608 B  attn_out bf16
  // split-K partials overlay the dead qkv region:
  // 1376 slots * 8192 u16 * 2B = 22,544,384 B; Ml after it (1,409,024 B); total < 25,165,824 B
  u16*    Opart = (u16*)(ws + 16777216);
  float2* Mlb   = (float2*)(ws + 16777216 + 22544384);

  k_prep1<<<6144, 256, 0, stream>>>(x, Wqkv, Wo, xb, wqkvT, woT);
  k_gemm64<false><<<dim3(64, 24), 256, 0, stream>>>(xb, wqkvT, qkv, 4096, 3072, 1024);
  k_prep2<<<3072, 256, 0, stream>>>(qkv, qw, kw, cosp, sinp, Qb, Kb, Vtb);
  k_attn<<<dim3(46, 32), 256, 0, stream>>>(Qb, Kb, Vtb, AO, Opart, Mlb);
  k_comb<<<dim3(13, 32), 256, 0, stream>>>(Opart, Mlb, AO);
  k_gemm64<true><<<dim3(64, 8), 256, 0, stream>>>(AO, woT, out, 4096, 1024, 1024);
}

// Round 28
// 129.083 us; speedup vs baseline: 1.0533x; 1.0009x over previous
//
#include <hip/hip_runtime.h>
#include <hip/hip_bf16.h>

typedef __attribute__((ext_vector_type(8))) short bh8;   // 8 bf16 in 4 VGPRs
typedef __attribute__((ext_vector_type(4))) float f4;    // MFMA accumulator

typedef unsigned short u16;
typedef unsigned int u32;

__device__ inline u16 f2b(float f) {
  __hip_bfloat16 h = __float2bfloat16(f);
  union { __hip_bfloat16 h; u16 u; } v; v.h = h; return v.u;
}
__device__ inline float b2f(u16 b) {
  union { u32 u; float f; } v; v.u = ((u32)b) << 16;
  return v.f;
}

// async global->LDS, 16B per lane; LDS dest is wave-uniform base + lane*16
__device__ __forceinline__ void gload16(const u16* g, u16* l) {
  __builtin_amdgcn_global_load_lds(
      (__attribute__((address_space(1))) void*)(g),
      (__attribute__((address_space(3))) void*)(l),
      16, 0, 0);
}

// ---------------- fused prep 1: cast x to bf16 (fat blocks) + both weight transposes ----------------
__global__ __launch_bounds__(256) void k_prep1(const float* __restrict__ x,
                                               const float* __restrict__ Wqkv,
                                               const float* __restrict__ Wo,
                                               u16* __restrict__ xb,
                                               u16* __restrict__ wqkvT,
                                               u16* __restrict__ woT) {
  int idx = blockIdx.x;
  if (idx < 2048) {
    int i = (idx * 256 + threadIdx.x) * 8;
    float4 v0 = *(const float4*)&x[i];
    float4 v1 = *(const float4*)&x[i + 4];
    ushort4 o0, o1;
    o0.x = f2b(v0.x); o0.y = f2b(v0.y); o0.z = f2b(v0.z); o0.w = f2b(v0.w);
    o1.x = f2b(v1.x); o1.y = f2b(v1.y); o1.z = f2b(v1.z); o1.w = f2b(v1.w);
    *(ushort4*)&xb[i]     = o0;
    *(ushort4*)&xb[i + 4] = o1;
    return;
  }
  __shared__ u16 t[32][33];
  const float* W; u16* WT; int K, N, bxi, byi;
  if (idx < 5120) {
    int id2 = idx - 2048;               // 96 x 32
    W = Wqkv; WT = wqkvT; K = 1024; N = 3072;
    bxi = id2 % 96; byi = id2 / 96;
  } else {
    int id2 = idx - 5120;               // 32 x 32
    W = Wo; WT = woT; K = 1024; N = 1024;
    bxi = id2 & 31; byi = id2 >> 5;
  }
  int bx = bxi * 32, by = byi * 32;
  int xx = threadIdx.x & 31, yy = threadIdx.x >> 5;
  for (int j = 0; j < 4; ++j) {
    int r = yy + j * 8;
    t[r][xx] = f2b(W[(size_t)(by + r) * N + bx + xx]);
  }
  __syncthreads();
  for (int j = 0; j < 4; ++j) {
    int r = yy + j * 8;
    WT[(size_t)(bx + r) * K + by + xx] = t[xx][r];
  }
}

// ---------------- GEMM 64x128 tile, XOR-swizzled LDS (proven R24 skeleton), both GEMMs ----------------
// 48 KB LDS -> 3 blocks/CU (12 waves/CU). GEMM1: grid (64,24)=1536 blocks = 2 even
// occupancy rounds. GEMM2: grid (64,8)=512 blocks, all resident in one round.
template <bool F32OUT>
__global__ __launch_bounds__(256) void k_gemm64(const u16* __restrict__ A,
                                                const u16* __restrict__ Bt,
                                                void* __restrict__ Cout,
                                                int M, int N, int K) {
  __shared__ u16 As[2][64 * 64];    // 16 KB
  __shared__ u16 Bs[2][128 * 64];   // 32 KB
  const int tid = threadIdx.x;
  const int lane = tid & 63, wid = tid >> 6;
  const int l15 = lane & 15, lg = lane >> 4;
  const int bm = blockIdx.x * 64, bn = blockIdx.y * 128;
  const int wr = (wid >> 1) * 32, wc = (wid & 1) * 64;

  f4 acc[2][4] = {};

  // staging: wave stages A rows [wid*16, +16) (2 gloads) and B rows [wid*32, +32) (4 gloads)
  const int arow = wid * 16 + (lane >> 3);
  const int brow = wid * 32 + (lane >> 3);
  const int scol = ((lane & 7) ^ ((lane >> 3) & 7)) * 8;   // all staged rows ≡ (lane>>3) mod 8
  const u16* gA = A  + (size_t)(bm + arow) * K + scol;
  const u16* gB = Bt + (size_t)(bn + brow) * K + scol;

  const int nk = K >> 6;

#define STAGE64(T)                                                 \
  {                                                                \
    int kb_ = (T) << 6; int bf_ = (T) & 1;                         \
    u16* la = &As[bf_][(wid * 16) * 64];                           \
    gload16(gA + kb_, la);                                         \
    gload16(gA + kb_ + (size_t)8 * K, la + 8 * 64);                \
    u16* lb = &Bs[bf_][(wid * 32) * 64];                           \
    const u16* gb = gB + kb_;                                      \
    _Pragma("unroll")                                              \
    for (int c = 0; c < 4; ++c) {                                  \
      gload16(gb, lb);                                             \
      gb += (size_t)8 * K; lb += 8 * 64;                           \
    }                                                              \
  }

  STAGE64(0);
  __syncthreads();

  for (int t = 0; t < nk; ++t) {
    if (t + 1 < nk) STAGE64(t + 1);
    const u16* as = &As[t & 1][0];
    const u16* bs = &Bs[t & 1][0];
    #pragma unroll
    for (int kk = 0; kk < 2; ++kk) {
      bh8 a[2], b[4];
      #pragma unroll
      for (int m = 0; m < 2; ++m)
        a[m] = *(const bh8*)&as[(wr + m * 16 + l15) * 64 + (((kk * 4 + lg) ^ (l15 & 7)) * 8)];
      #pragma unroll
      for (int n = 0; n < 4; ++n)
        b[n] = *(const bh8*)&bs[(wc + n * 16 + l15) * 64 + (((kk * 4 + lg) ^ (l15 & 7)) * 8)];
      #pragma unroll
      for (int m = 0; m < 2; ++m)
        #pragma unroll
        for (int n = 0; n < 4; ++n)
          acc[m][n] = __builtin_amdgcn_mfma_f32_16x16x32_bf16(a[m], b[n], acc[m][n], 0, 0, 0);
    }
    __syncthreads();
  }
#undef STAGE64

  for (int m = 0; m < 2; ++m)
    for (int n = 0; n < 4; ++n)
      for (int r = 0; r < 4; ++r) {
        int row = bm + wr + m * 16 + lg * 4 + r;
        int col = bn + wc + n * 16 + l15;
        float v = acc[m][n][r];
        if constexpr (F32OUT) ((float*)Cout)[(size_t)row * N + col] = v;
        else                  ((u16*)Cout)[(size_t)row * N + col]  = f2b(v);
      }
}

// ---------------- fused prep 2: vectorized RMSNorm+RoPE (Q,K) + vectorized V transpose ----------------
__global__ __launch_bounds__(256) void k_prep2(const u16* __restrict__ qkv,
                                               const float* __restrict__ qw,
                                               const float* __restrict__ kw,
                                               const float* __restrict__ cosp,
                                               const float* __restrict__ sinp,
                                               u16* __restrict__ Q,
                                               u16* __restrict__ K,
                                               u16* __restrict__ Vt) {
  const float CSC = 0.125f * 1.44269504088896f;
  int idx = blockIdx.x;
  if (idx < 2048) {
    int wid = threadIdx.x >> 6, lane = threadIdx.x & 63;
    int gw = idx * 4 + wid;
    int isK = gw & 1;
    int bl = gw >> 1;
    int l = bl & 2047, b = bl >> 11;
    int h = lane >> 2, qd = lane & 3;
    const u16* src = qkv + (size_t)bl * 3072 + isK * 1024 + h * 64 + qd * 8;
    bh8 t1 = *(const bh8*)src;
    bh8 t2 = *(const bh8*)(src + 32);
    float a1[8], a2[8];
    float ss = 0.0f;
    #pragma unroll
    for (int j = 0; j < 8; ++j) {
      a1[j] = b2f((u16)t1[j]); a2[j] = b2f((u16)t2[j]);
      ss += a1[j] * a1[j] + a2[j] * a2[j];
    }
    ss += __shfl_xor(ss, 1, 64);
    ss += __shfl_xor(ss, 2, 64);
    float rr = rsqrtf(ss * (1.0f / 64.0f) + 1e-6f);
    const float* wt = isK ? kw : qw;
    float w1[8], w2[8], cc[8], sn[8];
    *(float4*)&w1[0] = *(const float4*)&wt[qd * 8];
    *(float4*)&w1[4] = *(const float4*)&wt[qd * 8 + 4];
    *(float4*)&w2[0] = *(const float4*)&wt[32 + qd * 8];
    *(float4*)&w2[4] = *(const float4*)&wt[32 + qd * 8 + 4];
    *(float4*)&cc[0] = *(const float4*)&cosp[l * 32 + qd * 8];
    *(float4*)&cc[4] = *(const float4*)&cosp[l * 32 + qd * 8 + 4];
    *(float4*)&sn[0] = *(const float4*)&sinp[l * 32 + qd * 8];
    *(float4*)&sn[4] = *(const float4*)&sinp[l * 32 + qd * 8 + 4];
    float scl = isK ? 1.0f : CSC;
    bh8 o1, o2;
    #pragma unroll
    for (int j = 0; j < 8; ++j) {
      float x1 = a1[j] * rr * w1[j];
      float x2 = a2[j] * rr * w2[j];
      o1[j] = (short)f2b((x1 * cc[j] - x2 * sn[j]) * scl);
      o2[j] = (short)f2b((x1 * sn[j] + x2 * cc[j]) * scl);
    }
    u16* dst = (isK ? K : Q) + ((size_t)(b * 16 + h) * 2048 + l) * 64 + qd * 8;
    *(bh8*)dst = o1;
    *(bh8*)(dst + 32) = o2;
  } else {
    // vectorized V transpose: [64 l][64 d] tile per block, bh8 on both global sides
    __shared__ u16 tt[64][66];
    int v = idx - 2048;                 // 0..1023: bh (32) x l-tile (32)
    int bh = v >> 5, lt = v & 31;
    int b = bh >> 4, h = bh & 15;
    int lb = lt * 64;
    const u16* src = qkv + (size_t)b * 2048 * 3072 + 2048 + h * 64;
    int r0 = threadIdx.x >> 3, c0 = (threadIdx.x & 7) * 8;
    *(bh8*)&tt[r0][c0]      = *(const bh8*)&src[(size_t)(lb + r0) * 3072 + c0];
    *(bh8*)&tt[r0 + 32][c0] = *(const bh8*)&src[(size_t)(lb + r0 + 32) * 3072 + c0];
    __syncthreads();
    u16* dst = Vt + (size_t)bh * 64 * 2048;
    int d0 = threadIdx.x >> 3, l0 = (threadIdx.x & 7) * 8;
    bh8 o0, o1;
    #pragma unroll
    for (int j = 0; j < 8; ++j) {
      o0[j] = (short)tt[l0 + j][d0];
      o1[j] = (short)tt[l0 + j][d0 + 32];
    }
    *(bh8*)&dst[(size_t)d0 * 2048 + lb + l0]        = o0;
    *(bh8*)&dst[(size_t)(d0 + 32) * 2048 + lb + l0] = o1;
  }
}

// ---------------- flash attention, causal; R17 proven best (XCD-grouped bh, defer-max) ----------------
__global__ __launch_bounds__(256, 3) void k_attn(const u16* __restrict__ Q,
                                                 const u16* __restrict__ K,
                                                 const u16* __restrict__ Vt,
                                                 u16* __restrict__ O,
                                                 u16* __restrict__ Opart,
                                                 float2* __restrict__ Ml) {
  __shared__ u16 Ks[2][64 * 64];   // [k-local][d], XOR-swizzled chunks
  __shared__ u16 Vs[2][64 * 64];   // [d][k-local], XOR-swizzled chunks
  __shared__ u16 Pl[4][32][64];    // per-wave P, XOR-swizzled 16B chunks

  const int wid = threadIdx.x >> 6, lane = threadIdx.x & 63;
  const int l15 = lane & 15, lg = lane >> 4;

  // XCD-grouped block remap (1472 = 8 XCD * 4 bh * 46 chunks)
  const int linear = (int)blockIdx.y * 46 + (int)blockIdx.x;
  const int xcd = linear & 7;
  const int rest = linear >> 3;
  const int bh = xcd * 4 + (rest & 3);
  const int chunkIdx = rest >> 2;          // 0..45; chunk 0 of all bh dispatch first
  const int b = bh >> 4, h = bh & 15;

  const int ctab[17] = {0,1,2,3,5,7,9,11,14,17,20,24,28,32,36,41,46};
  const int id = 45 - chunkIdx;            // longest chunks first
  int qt = 0;
  #pragma unroll
  for (int qq = 0; qq < 16; ++qq)
    if (id >= ctab[qq + 1]) qt = qq + 1;
  const int part = id - ctab[qt];
  const int ways = ctab[qt + 1] - ctab[qt];
  const int T = 2 * qt + 2;
  const int t0 = part * T / ways;
  const int t1 = (part + 1) * T / ways;
  const int slot = (ways == 1) ? -1 : bh * 43 + (id - 3);

  const int qb = qt * 128 + wid * 32;

  const u16* Qp = Q  + (size_t)bh * 2048 * 64;
  const u16* Kp = K  + (size_t)bh * 2048 * 64;
  const u16* Vp = Vt + (size_t)bh * 64 * 2048;

  const int sr0 = wid * 8 + (lane >> 3);
  const int sc  = lane & 7;

  bh8 aq[2][2];
  #pragma unroll
  for (int qi = 0; qi < 2; ++qi)
    #pragma unroll
    for (int hh = 0; hh < 2; ++hh)
      aq[qi][hh] = *(const bh8*)&Qp[(size_t)(qb + qi * 16 + l15) * 64 + hh * 32 + lg * 8];

  bh8 ones;
  #pragma unroll
  for (int j = 0; j < 8; ++j) ones[j] = (short)0x3F80;

  f4 acc[2][4] = {};
  float mrow[2] = {-1e30f, -1e30f};   // log2 domain
  float lrow[2] = {0.0f, 0.0f};

  const int tmax = (qb + 31) >> 6;

  // prologue: stage tile t0
  {
    int kb0 = t0 * 64;
    int r0 = sr0, r1 = 32 + sr0;
    gload16(Kp + (size_t)(kb0 + r0) * 64 + (size_t)((sc ^ (r0 & 7)) * 8), &Ks[t0 & 1][(wid * 8) * 64]);
    gload16(Kp + (size_t)(kb0 + r1) * 64 + (size_t)((sc ^ (r1 & 7)) * 8), &Ks[t0 & 1][(32 + wid * 8) * 64]);
    gload16(Vp + (size_t)r0 * 2048 + kb0 + (size_t)((sc ^ (r0 & 7)) * 8), &Vs[t0 & 1][(wid * 8) * 64]);
    gload16(Vp + (size_t)r1 * 2048 + kb0 + (size_t)((sc ^ (r1 & 7)) * 8), &Vs[t0 & 1][(32 + wid * 8) * 64]);
  }
  __syncthreads();

  for (int t = t0; t < t1; ++t) {
    if (t + 1 < t1) {
      int kb = (t + 1) * 64;
      int nb = (t + 1) & 1;
      int r0 = sr0, r1 = 32 + sr0;
      gload16(Kp + (size_t)(kb + r0) * 64 + (size_t)((sc ^ (r0 & 7)) * 8), &Ks[nb][(wid * 8) * 64]);
      gload16(Kp + (size_t)(kb + r1) * 64 + (size_t)((sc ^ (r1 & 7)) * 8), &Ks[nb][(32 + wid * 8) * 64]);
      gload16(Vp + (size_t)r0 * 2048 + kb + (size_t)((sc ^ (r0 & 7)) * 8), &Vs[nb][(wid * 8) * 64]);
      gload16(Vp + (size_t)r1 * 2048 + kb + (size_t)((sc ^ (r1 & 7)) * 8), &Vs[nb][(32 + wid * 8) * 64]);
    }
    if (t <= tmax) {
      const int kb = t * 64;
      const bool masked = (t == tmax);
      const u16* ks = &Ks[t & 1][0];
      const u16* vs = &Vs[t & 1][0];

      // ---- QK^T (swapped): D col=q; Q pre-scaled (log2 domain) ----
      f4 sc4[4][2] = {};
      __builtin_amdgcn_s_setprio(1);
      #pragma unroll
      for (int kq = 0; kq < 4; ++kq) {
        int row = kq * 16 + l15;
        int cs = row & 7;
        bh8 ka0 = *(const bh8*)&ks[row * 64 + ((0 + lg) ^ cs) * 8];
        bh8 ka1 = *(const bh8*)&ks[row * 64 + ((4 + lg) ^ cs) * 8];
        #pragma unroll
        for (int qi = 0; qi < 2; ++qi) {
          sc4[kq][qi] = __builtin_amdgcn_mfma_f32_16x16x32_bf16(ka0, aq[qi][0], sc4[kq][qi], 0, 0, 0);
          sc4[kq][qi] = __builtin_amdgcn_mfma_f32_16x16x32_bf16(ka1, aq[qi][1], sc4[kq][qi], 0, 0, 0);
        }
      }
      __builtin_amdgcn_s_setprio(0);

      // ---- online softmax (log2 domain), defer-max THR=8, mask only diag ----
      #pragma unroll
      for (int qi = 0; qi < 2; ++qi) {
        if (masked) {
          int q = qb + qi * 16 + l15;
          #pragma unroll
          for (int kq = 0; kq < 4; ++kq)
            #pragma unroll
            for (int r = 0; r < 4; ++r)
              if (kb + kq * 16 + lg * 4 + r > q) sc4[kq][qi][r] = -1e30f;
        }
        float mx = -1e30f;
        #pragma unroll
        for (int kq = 0; kq < 4; ++kq)
          #pragma unroll
          for (int r = 0; r < 4; ++r)
            mx = fmaxf(mx, sc4[kq][qi][r]);
        mx = fmaxf(mx, __shfl_xor(mx, 16, 64));
        mx = fmaxf(mx, __shfl_xor(mx, 32, 64));
        if (__any(mx > mrow[qi] + 8.0f)) {
          float mnew = fmaxf(mrow[qi], mx);
          float fac = exp2f(mrow[qi] - mnew);
          mrow[qi] = mnew;
          lrow[qi] *= fac;
          #pragma unroll
          for (int n = 0; n < 4; ++n)
            #pragma unroll
            for (int r = 0; r < 4; ++r) acc[qi][n][r] *= fac;
        }
        #pragma unroll
        for (int kq = 0; kq < 4; ++kq)
          #pragma unroll
          for (int r = 0; r < 4; ++r)
            sc4[kq][qi][r] = exp2f(sc4[kq][qi][r] - mrow[qi]);
      }

      // ---- P -> per-wave LDS (XOR-swizzled 16B chunks; DS pipe) ----
      char* plb = (char*)&Pl[wid][0][0];
      #pragma unroll
      for (int qi = 0; qi < 2; ++qi) {
        int row = qi * 16 + l15;
        #pragma unroll
        for (int kq = 0; kq < 4; ++kq) {
          ushort4 w4;
          w4.x = f2b(sc4[kq][qi][0]); w4.y = f2b(sc4[kq][qi][1]);
          w4.z = f2b(sc4[kq][qi][2]); w4.w = f2b(sc4[kq][qi][3]);
          int ch = (kq * 2 + (lg >> 1)) ^ (row & 7);
          *(ushort4*)(plb + row * 128 + ch * 16 + (lg & 1) * 8) = w4;
        }
      }
      asm volatile("s_waitcnt lgkmcnt(0)" ::: "memory");
      __builtin_amdgcn_sched_barrier(0);

      // ---- PV (double-swapped) + row-sum via ones-MFMA ----
      f4 sum0 = {}, sum1 = {};
      __builtin_amdgcn_s_setprio(1);
      #pragma unroll
      for (int g = 0; g < 2; ++g) {
        bh8 pb0 = *(const bh8*)(plb + l15 * 128 + (((g * 4 + lg) ^ (l15 & 7)) * 16));
        bh8 pb1 = *(const bh8*)(plb + (16 + l15) * 128 + (((g * 4 + lg) ^ (l15 & 7)) * 16));
        #pragma unroll
        for (int n = 0; n < 4; ++n) {
          int row = n * 16 + l15;
          bh8 va = *(const bh8*)&vs[row * 64 + (((g * 4 + lg) ^ (row & 7)) * 8)];
          acc[0][n] = __builtin_amdgcn_mfma_f32_16x16x32_bf16(va, pb0, acc[0][n], 0, 0, 0);
          acc[1][n] = __builtin_amdgcn_mfma_f32_16x16x32_bf16(va, pb1, acc[1][n], 0, 0, 0);
        }
        sum0 = __builtin_amdgcn_mfma_f32_16x16x32_bf16(ones, pb0, sum0, 0, 0, 0);
        sum1 = __builtin_amdgcn_mfma_f32_16x16x32_bf16(ones, pb1, sum1, 0, 0, 0);
      }
      __builtin_amdgcn_s_setprio(0);
      lrow[0] += sum0[0];
      lrow[1] += sum1[0];
    }
    __syncthreads();
  }

  if (slot < 0) {
    #pragma unroll
    for (int qi = 0; qi < 2; ++qi) {
      float inv = 1.0f / lrow[qi];
      int q = qb + qi * 16 + l15;
      #pragma unroll
      for (int n = 0; n < 4; ++n) {
        ushort4 w4;
        w4.x = f2b(acc[qi][n][0] * inv);
        w4.y = f2b(acc[qi][n][1] * inv);
        w4.z = f2b(acc[qi][n][2] * inv);
        w4.w = f2b(acc[qi][n][3] * inv);
        *(ushort4*)&O[((size_t)b * 2048 + q) * 1024 + h * 64 + n * 16 + lg * 4] = w4;
      }
    }
  } else {
    u16* op = Opart + (size_t)slot * 8192;
    #pragma unroll
    for (int qi = 0; qi < 2; ++qi) {
      int rloc = wid * 32 + qi * 16 + l15;
      #pragma unroll
      for (int n = 0; n < 4; ++n) {
        ushort4 w4;
        w4.x = f2b(acc[qi][n][0]); w4.y = f2b(acc[qi][n][1]);
        w4.z = f2b(acc[qi][n][2]); w4.w = f2b(acc[qi][n][3]);
        *(ushort4*)&op[(size_t)rloc * 64 + n * 16 + lg * 4] = w4;
      }
      if (lg == 0) Ml[slot * 128 + rloc] = make_float2(mrow[qi], lrow[qi]);
    }
  }
}

// ---------------- combine split-K partials (2..5-way, 128-row slots) ----------------
__global__ __launch_bounds__(256) void k_comb(const u16* __restrict__ Opart,
                                              const float2* __restrict__ Ml,
                                              u16* __restrict__ O) {
  const int ctab[17] = {0,1,2,3,5,7,9,11,14,17,20,24,28,32,36,41,46};
  int qt = 3 + (int)blockIdx.x;     // 3..15
  int bh = blockIdx.y;
  int b = bh >> 4, h = bh & 15;
  int ways = ctab[qt + 1] - ctab[qt];
  int base = bh * 43 + ctab[qt] - 3;
  int row = threadIdx.x >> 1;
  int db  = (threadIdx.x & 1) * 32;

  float2 ml[5]; float wgt[5];
  float M = -1e30f;
  #pragma unroll
  for (int w = 0; w < 5; ++w)
    if (w < ways) { ml[w] = Ml[(base + w) * 128 + row]; M = fmaxf(M, ml[w].x); }
  float l = 0.0f;
  #pragma unroll
  for (int w = 0; w < 5; ++w)
    if (w < ways) { wgt[w] = exp2f(ml[w].x - M); l += wgt[w] * ml[w].y; }
  float inv = 1.0f / l;

  u16* dst = O + ((size_t)b * 2048 + qt * 128 + row) * 1024 + h * 64 + db;
  #pragma unroll
  for (int j = 0; j < 32; j += 8) {
    float a[8] = {};
    #pragma unroll
    for (int w = 0; w < 5; ++w)
      if (w < ways) {
        bh8 v = *(const bh8*)&Opart[(size_t)(base + w) * 8192 + (size_t)row * 64 + db + j];
        #pragma unroll
        for (int e = 0; e < 8; ++e) a[e] += wgt[w] * b2f((u16)v[e]);
      }
    bh8 o;
    #pragma unroll
    for (int e = 0; e < 8; ++e) o[e] = (short)f2b(a[e] * inv);
    *(bh8*)&dst[j] = o;
  }
}

extern "C" void kernel_launch(void* const* d_in, const int* in_sizes, int n_in,
                              void* d_out, int out_size, void* d_ws, size_t ws_size,
                              hipStream_t stream) {
  (void)in_sizes; (void)n_in; (void)out_size; (void)ws_size;
  const float* x    = (const float*)d_in[0];
  const float* Wqkv = (const float*)d_in[1];
  const float* Wo   = (const float*)d_in[2];
  const float* qw   = (const float*)d_in[3];
  const float* kw   = (const float*)d_in[4];
  const float* cosp = (const float*)d_in[5];
  const float* sinp = (const float*)d_in[6];
  float* out = (float*)d_out;

  char* ws = (char*)d_ws;
  u16* xb    = (u16*)(ws);                 //  8,388,608 B  x bf16 [4096][1024]
  u16* wqkvT = (u16*)(ws + 8388608);       //  6,291,456 B  Wqkv^T bf16
  u16* woT   = (u16*)(ws + 14680064);      //  2,097,152 B  Wo^T bf16
  u16* qkv   = (u16*)(ws + 16777216);      // 25,165,824 B  qkv bf16 [4096][3072]
  u16* Qb    = (u16*)(ws + 41943040);      //  8,388,608 B  [B,H,L,D]
  u16* Kb    = (u16*)(ws + 50331648);      //  8,388,608 B
  u16* Vtb   = (u16*)(ws + 58720256);      //  8,388,608 B  [B,H,D,L]
  u16* AO    = (u16*)(ws + 67108864);      //  8,388,608 B  attn_out bf16
  // split-K partials overlay the dead qkv region:
  // 1376 slots * 8192 u16 * 2B = 22,544,384 B; Ml after it (1,409,024 B); total < 25,165,824 B
  u16*    Opart = (u16*)(ws + 16777216);
  float2* Mlb   = (float2*)(ws + 16777216 + 22544384);

  k_prep1<<<6144, 256, 0, stream>>>(x, Wqkv, Wo, xb, wqkvT, woT);
  k_gemm64<false><<<dim3(64, 24), 256, 0, stream>>>(xb, wqkvT, qkv, 4096, 3072, 1024);
  k_prep2<<<3072, 256, 0, stream>>>(qkv, qw, kw, cosp, sinp, Qb, Kb, Vtb);
  k_attn<<<dim3(46, 32), 256, 0, stream>>>(Qb, Kb, Vtb, AO, Opart, Mlb);
  k_comb<<<dim3(13, 32), 256, 0, stream>>>(Opart, Mlb, AO);
  k_gemm64<true><<<dim3(64, 8), 256, 0, stream>>>(AO, woT, out, 4096, 1024, 1024);
}